// Round 7
// baseline (19371.881 us; speedup 1.0000x reference)
//
#include <hip/hip_runtime.h>
#include <stdint.h>

// BasicNCA2D: 10 steps of depthwise7x7(reflect) -> concat -> fc0 -> BN(batch) -> relu -> fc1 -> masked update.
// B=8,H=256,W=256,C=16,HID=128. steps hardcoded to 10.
// RNG: JAX threefry, jax_threefry_partitionable=True: bits[i] = xor(threefry2x32(key,(0,i))).
//
// R6: R5 post-mortem showed stats was latency-bound (VALUBusy 15%): the conv's 196
// global loads/cell were previously hidden by the serial gram's DS work; the MFMA gram
// removed that cover. Fix: (a) split stats into nca_conv (conv only, no barriers, high
// occupancy) + nca_gram (coalesced read + LDS transpose + MFMA gram); (b) nca_conv uses
// 2-cell vertical strips: 8 rows x 7 cols = 112 loads/cell (was 196), 2x FMA per load.
// Conv accumulation order unchanged -> bit-identical output.

constexpr int Bn = 8;
constexpr int Hn = 256;
constexpr int Wn = 256;
constexpr int Cn = 16;
constexpr int HIDn = 128;
constexpr int NROW = Bn * Hn;              // 2048 cell-groups of 256
constexpr int NCELLS = Bn * Hn * Wn;       // 524288
constexpr int NPAIR = 528;                 // 32*33/2 unique second moments of y
constexpr int NSTAT = 560;                 // pairs + 32 first moments
constexpr int STEPS = 10;

typedef __attribute__((ext_vector_type(8))) short bf16x8;
typedef __attribute__((ext_vector_type(4))) float f32x4;

__host__ __device__ inline uint32_t rotl32(uint32_t v, int r) {
  return (v << r) | (v >> (32 - r));
}

// Threefry-2x32, 20 rounds, exactly as jax/_src/prng.py
__host__ __device__ inline void tf2x32(uint32_t k0, uint32_t k1,
                                       uint32_t& x0, uint32_t& x1) {
  uint32_t k2 = k0 ^ k1 ^ 0x1BD11BDAu;
  x0 += k0; x1 += k1;
  x0 += x1; x1 = rotl32(x1, 13); x1 ^= x0;
  x0 += x1; x1 = rotl32(x1, 15); x1 ^= x0;
  x0 += x1; x1 = rotl32(x1, 26); x1 ^= x0;
  x0 += x1; x1 = rotl32(x1,  6); x1 ^= x0;
  x0 += k1; x1 += k2 + 1u;
  x0 += x1; x1 = rotl32(x1, 17); x1 ^= x0;
  x0 += x1; x1 = rotl32(x1, 29); x1 ^= x0;
  x0 += x1; x1 = rotl32(x1, 16); x1 ^= x0;
  x0 += x1; x1 = rotl32(x1, 24); x1 ^= x0;
  x0 += k2; x1 += k0 + 2u;
  x0 += x1; x1 = rotl32(x1, 13); x1 ^= x0;
  x0 += x1; x1 = rotl32(x1, 15); x1 ^= x0;
  x0 += x1; x1 = rotl32(x1, 26); x1 ^= x0;
  x0 += x1; x1 = rotl32(x1,  6); x1 ^= x0;
  x0 += k0; x1 += k1 + 3u;
  x0 += x1; x1 = rotl32(x1, 17); x1 ^= x0;
  x0 += x1; x1 = rotl32(x1, 29); x1 ^= x0;
  x0 += x1; x1 = rotl32(x1, 16); x1 ^= x0;
  x0 += x1; x1 = rotl32(x1, 24); x1 ^= x0;
  x0 += k1; x1 += k2 + 4u;
  x0 += x1; x1 = rotl32(x1, 13); x1 ^= x0;
  x0 += x1; x1 = rotl32(x1, 15); x1 ^= x0;
  x0 += x1; x1 = rotl32(x1, 26); x1 ^= x0;
  x0 += x1; x1 = rotl32(x1,  6); x1 ^= x0;
  x0 += k2; x1 += k0 + 5u;
}

__device__ inline float cell_mask(uint32_t fk0, uint32_t fk1, uint32_t ci) {
  uint32_t a = 0u, b2 = ci;
  tf2x32(fk0, fk1, a, b2);
  uint32_t bits = a ^ b2;
  float u = __uint_as_float((bits >> 9) | 0x3f800000u) - 1.0f;
  return (u > 0.5f) ? 1.0f : 0.0f;
}

// fp32 -> bf16 bits, round-to-nearest-even
__device__ inline uint32_t f2bf(float f) {
  uint32_t u = __float_as_uint(f);
  return (u + 0x7fffu + ((u >> 16) & 1u)) >> 16;
}

// one-time prep:
//  w0bf [n=128][k=32] bf16 : w0bf[n*32+k] = bf16(fc0w[k*128+n])
//  w1p  [c=16][kl=128] bf16: n = (kl&7)*16 + (kl>>3); w1p[c*128+kl] = bf16(fc1w[n*16+c])
__global__ __launch_bounds__(256) void nca_prep(const float* __restrict__ fc0w,
                                                const float* __restrict__ fc1w,
                                                uint16_t* __restrict__ w0bf,
                                                uint16_t* __restrict__ w1p) {
  int i = blockIdx.x * 256 + threadIdx.x;  // 0..6143
  if (i < 4096) {
    int n = i >> 5, k = i & 31;
    w0bf[i] = (uint16_t)f2bf(fc0w[k * HIDn + n]);
  } else {
    int j = i - 4096;
    int c = j >> 7, kl = j & 127;
    int n = (kl & 7) * 16 + (kl >> 3);
    w1p[j] = (uint16_t)f2bf(fc1w[n * 16 + c]);
  }
}

// Conv pass: 2-cell vertical strip per thread. Block = (b, h0..h0+1), w = threadIdx.
// 8 input rows x 7 cols slide once through registers; each column load feeds both
// cells' FMAs. Writes y=[x|conv+b] bf16 to ybf. No gram, minimal LDS.
__global__ __launch_bounds__(256) void nca_conv(
    const float* __restrict__ x, const float* __restrict__ p0w,
    const float* __restrict__ p0b, uint16_t* __restrict__ ybf) {
  __shared__ float sW[784];
  __shared__ float sB[16];
  int t = threadIdx.x;
  int bid = blockIdx.x;
  int b = bid & 7;               // one image per XCD
  int h0 = (bid >> 3) * 2;
  for (int i = t; i < 784; i += 256) sW[i] = p0w[i];
  if (t < 16) sB[t] = p0b[t];
  __syncthreads();

  const float* xb = x + (size_t)b * (Hn * Wn * Cn);
  int w = t;
  float acc0[16], acc1[16];
#pragma unroll
  for (int c = 0; c < 16; c++) { acc0[c] = 0.0f; acc1[c] = 0.0f; }

#pragma unroll
  for (int r = 0; r < 8; r++) {
    int hi = h0 - 3 + r;
    hi = (hi < 0) ? -hi : ((hi >= Hn) ? (2 * Hn - 2 - hi) : hi);
    const float* xr = xb + (size_t)hi * (Wn * Cn);
#pragma unroll
    for (int dx = 0; dx < 7; dx++) {
      int ww = w + dx - 3;
      ww = (ww < 0) ? -ww : ((ww >= Wn) ? (2 * Wn - 2 - ww) : ww);
      const float4* p = reinterpret_cast<const float4*>(xr + (size_t)ww * Cn);
      float4 v0 = p[0], v1 = p[1], v2 = p[2], v3 = p[3];
      float v[16];
      v[0] = v0.x;  v[1] = v0.y;  v[2] = v0.z;  v[3] = v0.w;
      v[4] = v1.x;  v[5] = v1.y;  v[6] = v1.z;  v[7] = v1.w;
      v[8] = v2.x;  v[9] = v2.y;  v[10] = v2.z; v[11] = v2.w;
      v[12] = v3.x; v[13] = v3.y; v[14] = v3.z; v[15] = v3.w;
      if (r <= 6) {  // cell0: dy = r
        const float* wt = sW + (r * 7 + dx) * 16;
#pragma unroll
        for (int c = 0; c < 16; c++) acc0[c] += wt[c] * v[c];
      }
      if (r >= 1) {  // cell1: dy = r-1
        const float* wt = sW + ((r - 1) * 7 + dx) * 16;
#pragma unroll
        for (int c = 0; c < 16; c++) acc1[c] += wt[c] * v[c];
      }
    }
  }

  // pack & store both cells (center x reloaded, L1-hot)
  size_t ci0 = ((size_t)(b * Hn + h0) * Wn + w);
#pragma unroll
  for (int cell = 0; cell < 2; cell++) {
    size_t ci = ci0 + (size_t)cell * Wn;
    const float4* pc = reinterpret_cast<const float4*>(
        xb + ((size_t)(h0 + cell) * Wn + w) * Cn);
    float4 c0 = pc[0], c1 = pc[1], c2 = pc[2], c3 = pc[3];
    float xcv[16];
    xcv[0] = c0.x;  xcv[1] = c0.y;  xcv[2] = c0.z;  xcv[3] = c0.w;
    xcv[4] = c1.x;  xcv[5] = c1.y;  xcv[6] = c1.z;  xcv[7] = c1.w;
    xcv[8] = c2.x;  xcv[9] = c2.y;  xcv[10] = c2.z; xcv[11] = c2.w;
    xcv[12] = c3.x; xcv[13] = c3.y; xcv[14] = c3.z; xcv[15] = c3.w;
    const float* acc = cell ? acc1 : acc0;
    uint32_t pk[16];
#pragma unroll
    for (int q = 0; q < 8; q++)
      pk[q] = f2bf(xcv[2 * q]) | (f2bf(xcv[2 * q + 1]) << 16);
#pragma unroll
    for (int q = 0; q < 8; q++)
      pk[8 + q] = f2bf(acc[2 * q] + sB[2 * q]) |
                  (f2bf(acc[2 * q + 1] + sB[2 * q + 1]) << 16);
    uint4* yp = reinterpret_cast<uint4*>(ybf + ci * 32);
    yp[0] = make_uint4(pk[0], pk[1], pk[2], pk[3]);
    yp[1] = make_uint4(pk[4], pk[5], pk[6], pk[7]);
    yp[2] = make_uint4(pk[8], pk[9], pk[10], pk[11]);
    yp[3] = make_uint4(pk[12], pk[13], pk[14], pk[15]);
  }
}

// Gram pass: 256 cells/block. Coalesced ybf load -> channel-major swizzled LDS ->
// per-wave 32x32 gram of 64 cells via 6 MFMAs (+4 with B=ones for moments) ->
// block partials [560].
__global__ __launch_bounds__(256) void nca_gram(
    const uint16_t* __restrict__ ybf, float* __restrict__ partials) {
  __shared__ __align__(16) short sYT[32 * 256];  // elem (c,k) at c*256+(k^((c&7)<<3)); aliased as f32 gram[4][1024]
  __shared__ float sMom[4 * 32];
  int t = threadIdx.x;
  int lane = t & 63, wid = t >> 6;
  int row = blockIdx.x;

  const uint4* yp = reinterpret_cast<const uint4*>(ybf + ((size_t)row * 256 + t) * 32);
  uint4 q0 = yp[0], q1 = yp[1], q2 = yp[2], q3 = yp[3];
  uint32_t pk[16] = {q0.x, q0.y, q0.z, q0.w, q1.x, q1.y, q1.z, q1.w,
                     q2.x, q2.y, q2.z, q2.w, q3.x, q3.y, q3.z, q3.w};
#pragma unroll
  for (int c = 0; c < 32; c++) {
    uint16_t hv = (c & 1) ? (uint16_t)(pk[c >> 1] >> 16) : (uint16_t)(pk[c >> 1] & 0xffffu);
    sYT[c * 256 + (t ^ ((c & 7) << 3))] = (short)hv;
  }
  __syncthreads();

  int colc = lane & 15, kg = lane >> 4;
  f32x4 g00 = {0.f, 0.f, 0.f, 0.f}, g01 = g00, g11 = g00, m0 = g00, m1 = g00;
  bf16x8 ones;
#pragma unroll
  for (int e = 0; e < 8; e++) ones[e] = (short)0x3F80;  // bf16 1.0
#pragma unroll
  for (int s2 = 0; s2 < 2; s2++) {
    int kbase = wid * 64 + s2 * 32 + kg * 8;
    int ch0 = colc, ch1 = 16 + colc;
    bf16x8 f0 = *reinterpret_cast<const bf16x8*>(sYT + ch0 * 256 + (kbase ^ ((ch0 & 7) << 3)));
    bf16x8 f1 = *reinterpret_cast<const bf16x8*>(sYT + ch1 * 256 + (kbase ^ ((ch1 & 7) << 3)));
    g00 = __builtin_amdgcn_mfma_f32_16x16x32_bf16(f0, f0, g00, 0, 0, 0);
    g01 = __builtin_amdgcn_mfma_f32_16x16x32_bf16(f0, f1, g01, 0, 0, 0);
    g11 = __builtin_amdgcn_mfma_f32_16x16x32_bf16(f1, f1, g11, 0, 0, 0);
    m0  = __builtin_amdgcn_mfma_f32_16x16x32_bf16(f0, ones, m0, 0, 0, 0);
    m1  = __builtin_amdgcn_mfma_f32_16x16x32_bf16(f1, ones, m1, 0, 0, 0);
  }
  if (colc == 0) {
#pragma unroll
    for (int r = 0; r < 4; r++) {
      sMom[wid * 32 + kg * 4 + r] = m0[r];
      sMom[wid * 32 + 16 + kg * 4 + r] = m1[r];
    }
  }
  __syncthreads();  // all waves done with sYT -> alias as gram
  float* sG = reinterpret_cast<float*>(sYT);  // [4][32][32]
  {
    float* sGw = sG + wid * 1024;
#pragma unroll
    for (int r = 0; r < 4; r++) {
      int rr = kg * 4 + r;
      sGw[rr * 32 + colc] = g00[r];
      sGw[rr * 32 + 16 + colc] = g01[r];
      sGw[(16 + rr) * 32 + 16 + colc] = g11[r];
    }
  }
  __syncthreads();

  float* outp = partials + (size_t)row * NSTAT;
  for (int e = t; e < NSTAT; e += 256) {
    float acc;
    if (e < NPAIR) {
      int ee = e, i = 0;
      while (ee >= (32 - i)) { ee -= (32 - i); i++; }
      int j = i + ee;
      int gi = i * 32 + j;
      acc = sG[gi] + sG[1024 + gi] + sG[2048 + gi] + sG[3072 + gi];
    } else {
      int i = e - NPAIR;
      acc = sMom[i] + sMom[32 + i] + sMom[64 + i] + sMom[96 + i];
    }
    outp[e] = acc;
  }
}

// Reduce partials across the 2048 groups (fp64) -> sred[560]
__global__ __launch_bounds__(256) void nca_reduceA(
    const float* __restrict__ partials, double* __restrict__ sred) {
  __shared__ double red[256];
  int e = blockIdx.x;
  int t = threadIdx.x;
  double acc = 0.0;
  for (int row = t; row < NROW; row += 256)
    acc += (double)partials[(size_t)row * NSTAT + e];
  red[t] = acc;
  __syncthreads();
  for (int s2 = 128; s2 > 0; s2 >>= 1) {
    if (t < s2) red[t] += red[t + s2];
    __syncthreads();
  }
  if (t == 0) sred[e] = red[0];
}

// Per-hid BN constants from moments. fc0_b cancels exactly.
__global__ __launch_bounds__(128) void nca_reduceB(
    const double* __restrict__ sred, const float* __restrict__ fc0w,
    const float* __restrict__ gamma, const float* __restrict__ beta,
    float* __restrict__ ss) {
  __shared__ double S[NSTAT];
  int t = threadIdx.x;
  for (int i = t; i < NSTAT; i += 128) S[i] = sred[i];
  __syncthreads();
  double wv[32];
#pragma unroll
  for (int k = 0; k < 32; k++) wv[k] = (double)fc0w[k * HIDn + t];
  double mean_g = 0.0, q = 0.0;
  int e = 0;
  for (int i = 0; i < 32; i++) {
    mean_g += wv[i] * S[NPAIR + i];
    q += wv[i] * wv[i] * S[e]; e++;
    for (int j = i + 1; j < 32; j++) { q += 2.0 * wv[i] * wv[j] * S[e]; e++; }
  }
  const double invN = 1.0 / (double)NCELLS;
  mean_g *= invN; q *= invN;
  double var = q - mean_g * mean_g;
  double scale = (double)gamma[t] / sqrt(var + 1e-5);
  ss[2 * t]     = (float)scale;
  ss[2 * t + 1] = (float)((double)beta[t] - mean_g * scale);
}

// MFMA update: per wave, 16-cell M-tiles. fc0: 8x mfma_16x16x32_bf16 (K=32);
// BN+relu on f32 accs; repack bf16 via per-wave LDS (XOR swizzle, k-permuted);
// fc1: 4x mfma_16x16x32_bf16 (K=128); residual+mask epilogue.
__global__ __launch_bounds__(256) void nca_update_mfma(
    const float* __restrict__ x, const uint16_t* __restrict__ ybf,
    const uint16_t* __restrict__ w0bf, const uint16_t* __restrict__ w1p,
    const float* __restrict__ ssg, float* __restrict__ xout,
    uint32_t fk0, uint32_t fk1) {
  __shared__ short hbuf[4][16 * 128];  // 4KB per wave
  int t = threadIdx.x;
  int lane = t & 63, wid = t >> 6;
  int col = lane & 15, g = lane >> 4;
  short* hb = hbuf[wid];

  bf16x8 b0[8];
#pragma unroll
  for (int nt = 0; nt < 8; nt++) {
    int n = nt * 16 + col;
    b0[nt] = *reinterpret_cast<const bf16x8*>(w0bf + n * 32 + g * 8);
  }
  bf16x8 b2[4];
#pragma unroll
  for (int kk = 0; kk < 4; kk++)
    b2[kk] = *reinterpret_cast<const bf16x8*>(w1p + col * 128 + kk * 32 + g * 8);
  float sc[8], sh[8];
#pragma unroll
  for (int nt = 0; nt < 8; nt++) {
    float2 v = reinterpret_cast<const float2*>(ssg)[nt * 16 + col];
    sc[nt] = v.x; sh[nt] = v.y;
  }

  uint32_t waveBase = (uint32_t)blockIdx.x * 1024u + (uint32_t)wid * 256u;
  for (int grp = 0; grp < 4; grp++) {
    uint32_t grpBase = waveBase + (uint32_t)grp * 64u;
    float mval = cell_mask(fk0, fk1, grpBase + (uint32_t)lane);
#pragma unroll 1
    for (int tt = 0; tt < 4; tt++) {
      uint32_t tb = grpBase + (uint32_t)tt * 16u;
      bf16x8 a0 = *reinterpret_cast<const bf16x8*>(
          ybf + (size_t)(tb + col) * 32 + g * 8);
      float xv[4];
#pragma unroll
      for (int r = 0; r < 4; r++)
        xv[r] = x[(size_t)(tb + g * 4 + r) * Cn + col];
      f32x4 h[8];
#pragma unroll
      for (int nt = 0; nt < 8; nt++) {
        f32x4 z = {0.f, 0.f, 0.f, 0.f};
        h[nt] = __builtin_amdgcn_mfma_f32_16x16x32_bf16(a0, b0[nt], z, 0, 0, 0);
      }
#pragma unroll
      for (int r = 0; r < 4; r++) {
        int m = g * 4 + r;
        uint32_t u[4];
#pragma unroll
        for (int q = 0; q < 4; q++) {
          float v0 = fmaxf(h[2 * q][r] * sc[2 * q] + sh[2 * q], 0.0f);
          float v1 = fmaxf(h[2 * q + 1][r] * sc[2 * q + 1] + sh[2 * q + 1], 0.0f);
          u[q] = f2bf(v0) | (f2bf(v1) << 16);
        }
        int idx = m * 128 + ((col * 8) ^ ((m & 7) << 3));
        *reinterpret_cast<uint4*>(hb + idx) = make_uint4(u[0], u[1], u[2], u[3]);
      }
      f32x4 dx = {0.f, 0.f, 0.f, 0.f};
#pragma unroll
      for (int kk = 0; kk < 4; kk++) {
        int idx = col * 128 + (((kk * 32) + g * 8) ^ ((col & 7) << 3));
        bf16x8 a2 = *reinterpret_cast<const bf16x8*>(hb + idx);
        dx = __builtin_amdgcn_mfma_f32_16x16x32_bf16(a2, b2[kk], dx, 0, 0, 0);
      }
#pragma unroll
      for (int r = 0; r < 4; r++) {
        int m = g * 4 + r;
        float mk = __shfl(mval, tt * 16 + m);
        float o = xv[r] + dx[r] * mk;
        if (col == 0) o = xv[r];
        xout[(size_t)(tb + m) * Cn + col] = o;
      }
    }
  }
}

extern "C" void kernel_launch(void* const* d_in, const int* in_sizes, int n_in,
                              void* d_out, int out_size, void* d_ws, size_t ws_size,
                              hipStream_t stream) {
  (void)in_sizes; (void)n_in; (void)out_size; (void)ws_size;
  const float* x0    = (const float*)d_in[0];
  const float* p0w   = (const float*)d_in[1];
  const float* p0b   = (const float*)d_in[2];
  const float* fc0w  = (const float*)d_in[3];
  // d_in[4] = fc0_b: cancels exactly in BatchNorm -> unused
  const float* gamma = (const float*)d_in[5];
  const float* beta  = (const float*)d_in[6];
  const float* fc1w  = (const float*)d_in[7];
  // d_in[8] = steps (=10, hardcoded)

  // workspace layout (~72 MB)
  size_t off = 0;
  float* ws_x = (float*)((char*)d_ws + off); off += (size_t)NCELLS * Cn * 4;        // 33.5 MiB
  uint16_t* ws_ybf = (uint16_t*)((char*)d_ws + off); off += (size_t)NCELLS * 32 * 2; // 33.5 MiB
  float* ws_part = (float*)((char*)d_ws + off); off += (size_t)NROW * NSTAT * 4;    // 4.6 MiB
  double* ws_sred = (double*)((char*)d_ws + off); off += (size_t)NSTAT * 8;
  float* ws_ss = (float*)((char*)d_ws + off); off += (size_t)HIDn * 2 * 4;
  uint16_t* ws_w0bf = (uint16_t*)((char*)d_ws + off); off += 4096 * 2;
  uint16_t* ws_w1p = (uint16_t*)((char*)d_ws + off); off += 2048 * 2;
  float* out = (float*)d_out;

  nca_prep<<<24, 256, 0, stream>>>(fc0w, fc1w, ws_w0bf, ws_w1p);

  const float* xin = x0;
  for (int s = 0; s < STEPS; s++) {
    uint32_t fk0 = 0u, fk1 = (uint32_t)s;
    tf2x32(0u, 42u, fk0, fk1);
    float* xo = (((STEPS - 1 - s) & 1) != 0) ? ws_x : out;

    nca_conv<<<Bn * Hn / 2, 256, 0, stream>>>(xin, p0w, p0b, ws_ybf);
    nca_gram<<<NROW, 256, 0, stream>>>(ws_ybf, ws_part);
    nca_reduceA<<<NSTAT, 256, 0, stream>>>(ws_part, ws_sred);
    nca_reduceB<<<1, 128, 0, stream>>>(ws_sred, fc0w, gamma, beta, ws_ss);
    nca_update_mfma<<<NCELLS / 1024, 256, 0, stream>>>(xin, ws_ybf, ws_w0bf,
                                                       ws_w1p, ws_ss, xo, fk0, fk1);
    xin = xo;
  }
}

// Round 8
// 1170.107 us; speedup vs baseline: 16.5557x; 16.5557x over previous
//
#include <hip/hip_runtime.h>
#include <stdint.h>

// BasicNCA2D: 10 steps of depthwise7x7(reflect) -> concat -> fc0 -> BN(batch) -> relu -> fc1 -> masked update.
// B=8,H=256,W=256,C=16,HID=128. steps hardcoded to 10.
// RNG: JAX threefry, jax_threefry_partitionable=True: bits[i] = xor(threefry2x32(key,(0,i))).
//
// R7: R6's split kept; nca_conv codegen fixed. R6 failure: #pragma unroll on the 8-row
// loop fully unrolled 56 load-heavy iterations -> 256 VGPR + 4.4GB scratch traffic/dispatch
// (VALUBusy 1%). Fix: dy-loop ROLLED (unroll 1), dx unrolled (R1's proven 92-VGPR shape),
// 2-cell vertical strip kept for ILP, __launch_bounds__(256,3) caps VGPR at 170 (no spill).
// Conv accumulation order per cell unchanged -> bit-identical output.

constexpr int Bn = 8;
constexpr int Hn = 256;
constexpr int Wn = 256;
constexpr int Cn = 16;
constexpr int HIDn = 128;
constexpr int NROW = Bn * Hn;              // 2048 cell-groups of 256
constexpr int NCELLS = Bn * Hn * Wn;       // 524288
constexpr int NPAIR = 528;                 // 32*33/2 unique second moments of y
constexpr int NSTAT = 560;                 // pairs + 32 first moments
constexpr int STEPS = 10;

typedef __attribute__((ext_vector_type(8))) short bf16x8;
typedef __attribute__((ext_vector_type(4))) float f32x4;

__host__ __device__ inline uint32_t rotl32(uint32_t v, int r) {
  return (v << r) | (v >> (32 - r));
}

// Threefry-2x32, 20 rounds, exactly as jax/_src/prng.py
__host__ __device__ inline void tf2x32(uint32_t k0, uint32_t k1,
                                       uint32_t& x0, uint32_t& x1) {
  uint32_t k2 = k0 ^ k1 ^ 0x1BD11BDAu;
  x0 += k0; x1 += k1;
  x0 += x1; x1 = rotl32(x1, 13); x1 ^= x0;
  x0 += x1; x1 = rotl32(x1, 15); x1 ^= x0;
  x0 += x1; x1 = rotl32(x1, 26); x1 ^= x0;
  x0 += x1; x1 = rotl32(x1,  6); x1 ^= x0;
  x0 += k1; x1 += k2 + 1u;
  x0 += x1; x1 = rotl32(x1, 17); x1 ^= x0;
  x0 += x1; x1 = rotl32(x1, 29); x1 ^= x0;
  x0 += x1; x1 = rotl32(x1, 16); x1 ^= x0;
  x0 += x1; x1 = rotl32(x1, 24); x1 ^= x0;
  x0 += k2; x1 += k0 + 2u;
  x0 += x1; x1 = rotl32(x1, 13); x1 ^= x0;
  x0 += x1; x1 = rotl32(x1, 15); x1 ^= x0;
  x0 += x1; x1 = rotl32(x1, 26); x1 ^= x0;
  x0 += x1; x1 = rotl32(x1,  6); x1 ^= x0;
  x0 += k0; x1 += k1 + 3u;
  x0 += x1; x1 = rotl32(x1, 17); x1 ^= x0;
  x0 += x1; x1 = rotl32(x1, 29); x1 ^= x0;
  x0 += x1; x1 = rotl32(x1, 16); x1 ^= x0;
  x0 += x1; x1 = rotl32(x1, 24); x1 ^= x0;
  x0 += k1; x1 += k2 + 4u;
  x0 += x1; x1 = rotl32(x1, 13); x1 ^= x0;
  x0 += x1; x1 = rotl32(x1, 15); x1 ^= x0;
  x0 += x1; x1 = rotl32(x1, 26); x1 ^= x0;
  x0 += x1; x1 = rotl32(x1,  6); x1 ^= x0;
  x0 += k2; x1 += k0 + 5u;
}

__device__ inline float cell_mask(uint32_t fk0, uint32_t fk1, uint32_t ci) {
  uint32_t a = 0u, b2 = ci;
  tf2x32(fk0, fk1, a, b2);
  uint32_t bits = a ^ b2;
  float u = __uint_as_float((bits >> 9) | 0x3f800000u) - 1.0f;
  return (u > 0.5f) ? 1.0f : 0.0f;
}

// fp32 -> bf16 bits, round-to-nearest-even
__device__ inline uint32_t f2bf(float f) {
  uint32_t u = __float_as_uint(f);
  return (u + 0x7fffu + ((u >> 16) & 1u)) >> 16;
}

// one-time prep:
//  w0bf [n=128][k=32] bf16 : w0bf[n*32+k] = bf16(fc0w[k*128+n])
//  w1p  [c=16][kl=128] bf16: n = (kl&7)*16 + (kl>>3); w1p[c*128+kl] = bf16(fc1w[n*16+c])
__global__ __launch_bounds__(256) void nca_prep(const float* __restrict__ fc0w,
                                                const float* __restrict__ fc1w,
                                                uint16_t* __restrict__ w0bf,
                                                uint16_t* __restrict__ w1p) {
  int i = blockIdx.x * 256 + threadIdx.x;  // 0..6143
  if (i < 4096) {
    int n = i >> 5, k = i & 31;
    w0bf[i] = (uint16_t)f2bf(fc0w[k * HIDn + n]);
  } else {
    int j = i - 4096;
    int c = j >> 7, kl = j & 127;
    int n = (kl & 7) * 16 + (kl >> 3);
    w1p[j] = (uint16_t)f2bf(fc1w[n * 16 + c]);
  }
}

// Conv pass: 2-cell vertical strip per thread, dy-loop ROLLED, dx unrolled.
// Block = (b, h0..h0+1), w = threadIdx. 8 input rows slide once; each loaded
// column feeds both cells. Writes y=[x|conv+b] bf16 to ybf.
__global__ __launch_bounds__(256, 3) void nca_conv(
    const float* __restrict__ x, const float* __restrict__ p0w,
    const float* __restrict__ p0b, uint16_t* __restrict__ ybf) {
  __shared__ float sW[784];
  __shared__ float sB[16];
  int t = threadIdx.x;
  int bid = blockIdx.x;
  int b = bid & 7;               // one image per XCD
  int h0 = (bid >> 3) * 2;
  for (int i = t; i < 784; i += 256) sW[i] = p0w[i];
  if (t < 16) sB[t] = p0b[t];
  __syncthreads();

  const float* xb = x + (size_t)b * (Hn * Wn * Cn);
  int w = t;
  float acc0[16], acc1[16];
#pragma unroll
  for (int c = 0; c < 16; c++) { acc0[c] = 0.0f; acc1[c] = 0.0f; }

#pragma unroll 1
  for (int r = 0; r < 8; r++) {
    int hi = h0 - 3 + r;
    hi = (hi < 0) ? -hi : ((hi >= Hn) ? (2 * Hn - 2 - hi) : hi);
    const float* xr = xb + (size_t)hi * (Wn * Cn);
    const float* wt0 = sW + r * 112;        // cell0 taps: dy = r       (valid r<=6)
    const float* wt1 = sW + (r - 1) * 112;  // cell1 taps: dy = r-1     (valid r>=1)
    bool c0 = (r <= 6), c1 = (r >= 1);
#pragma unroll
    for (int dx = 0; dx < 7; dx++) {
      int ww = w + dx - 3;
      ww = (ww < 0) ? -ww : ((ww >= Wn) ? (2 * Wn - 2 - ww) : ww);
      const float4* p = reinterpret_cast<const float4*>(xr + (size_t)ww * Cn);
      float4 v0 = p[0], v1 = p[1], v2 = p[2], v3 = p[3];
      float v[16];
      v[0] = v0.x;  v[1] = v0.y;  v[2] = v0.z;  v[3] = v0.w;
      v[4] = v1.x;  v[5] = v1.y;  v[6] = v1.z;  v[7] = v1.w;
      v[8] = v2.x;  v[9] = v2.y;  v[10] = v2.z; v[11] = v2.w;
      v[12] = v3.x; v[13] = v3.y; v[14] = v3.z; v[15] = v3.w;
      if (c0) {
        const float* wt = wt0 + dx * 16;
#pragma unroll
        for (int c = 0; c < 16; c++) acc0[c] += wt[c] * v[c];
      }
      if (c1) {
        const float* wt = wt1 + dx * 16;
#pragma unroll
        for (int c = 0; c < 16; c++) acc1[c] += wt[c] * v[c];
      }
    }
  }

  // pack & store both cells (center x reloaded, L1-hot)
  size_t ci0 = ((size_t)(b * Hn + h0) * Wn + w);
#pragma unroll
  for (int cell = 0; cell < 2; cell++) {
    size_t ci = ci0 + (size_t)cell * Wn;
    const float4* pc = reinterpret_cast<const float4*>(
        xb + ((size_t)(h0 + cell) * Wn + w) * Cn);
    float4 c0v = pc[0], c1v = pc[1], c2v = pc[2], c3v = pc[3];
    float xcv[16];
    xcv[0] = c0v.x;  xcv[1] = c0v.y;  xcv[2] = c0v.z;  xcv[3] = c0v.w;
    xcv[4] = c1v.x;  xcv[5] = c1v.y;  xcv[6] = c1v.z;  xcv[7] = c1v.w;
    xcv[8] = c2v.x;  xcv[9] = c2v.y;  xcv[10] = c2v.z; xcv[11] = c2v.w;
    xcv[12] = c3v.x; xcv[13] = c3v.y; xcv[14] = c3v.z; xcv[15] = c3v.w;
    const float* acc = cell ? acc1 : acc0;
    uint32_t pk[16];
#pragma unroll
    for (int q = 0; q < 8; q++)
      pk[q] = f2bf(xcv[2 * q]) | (f2bf(xcv[2 * q + 1]) << 16);
#pragma unroll
    for (int q = 0; q < 8; q++)
      pk[8 + q] = f2bf(acc[2 * q] + sB[2 * q]) |
                  (f2bf(acc[2 * q + 1] + sB[2 * q + 1]) << 16);
    uint4* yp = reinterpret_cast<uint4*>(ybf + ci * 32);
    yp[0] = make_uint4(pk[0], pk[1], pk[2], pk[3]);
    yp[1] = make_uint4(pk[4], pk[5], pk[6], pk[7]);
    yp[2] = make_uint4(pk[8], pk[9], pk[10], pk[11]);
    yp[3] = make_uint4(pk[12], pk[13], pk[14], pk[15]);
  }
}

// Gram pass: 256 cells/block. Coalesced ybf load -> channel-major swizzled LDS ->
// per-wave 32x32 gram of 64 cells via 6 MFMAs (+4 with B=ones for moments) ->
// block partials [560].
__global__ __launch_bounds__(256) void nca_gram(
    const uint16_t* __restrict__ ybf, float* __restrict__ partials) {
  __shared__ __align__(16) short sYT[32 * 256];  // elem (c,k) at c*256+(k^((c&7)<<3)); aliased as f32 gram[4][1024]
  __shared__ float sMom[4 * 32];
  int t = threadIdx.x;
  int lane = t & 63, wid = t >> 6;
  int row = blockIdx.x;

  const uint4* yp = reinterpret_cast<const uint4*>(ybf + ((size_t)row * 256 + t) * 32);
  uint4 q0 = yp[0], q1 = yp[1], q2 = yp[2], q3 = yp[3];
  uint32_t pk[16] = {q0.x, q0.y, q0.z, q0.w, q1.x, q1.y, q1.z, q1.w,
                     q2.x, q2.y, q2.z, q2.w, q3.x, q3.y, q3.z, q3.w};
#pragma unroll
  for (int c = 0; c < 32; c++) {
    uint16_t hv = (c & 1) ? (uint16_t)(pk[c >> 1] >> 16) : (uint16_t)(pk[c >> 1] & 0xffffu);
    sYT[c * 256 + (t ^ ((c & 7) << 3))] = (short)hv;
  }
  __syncthreads();

  int colc = lane & 15, kg = lane >> 4;
  f32x4 g00 = {0.f, 0.f, 0.f, 0.f}, g01 = g00, g11 = g00, m0 = g00, m1 = g00;
  bf16x8 ones;
#pragma unroll
  for (int e = 0; e < 8; e++) ones[e] = (short)0x3F80;  // bf16 1.0
#pragma unroll
  for (int s2 = 0; s2 < 2; s2++) {
    int kbase = wid * 64 + s2 * 32 + kg * 8;
    int ch0 = colc, ch1 = 16 + colc;
    bf16x8 f0 = *reinterpret_cast<const bf16x8*>(sYT + ch0 * 256 + (kbase ^ ((ch0 & 7) << 3)));
    bf16x8 f1 = *reinterpret_cast<const bf16x8*>(sYT + ch1 * 256 + (kbase ^ ((ch1 & 7) << 3)));
    g00 = __builtin_amdgcn_mfma_f32_16x16x32_bf16(f0, f0, g00, 0, 0, 0);
    g01 = __builtin_amdgcn_mfma_f32_16x16x32_bf16(f0, f1, g01, 0, 0, 0);
    g11 = __builtin_amdgcn_mfma_f32_16x16x32_bf16(f1, f1, g11, 0, 0, 0);
    m0  = __builtin_amdgcn_mfma_f32_16x16x32_bf16(f0, ones, m0, 0, 0, 0);
    m1  = __builtin_amdgcn_mfma_f32_16x16x32_bf16(f1, ones, m1, 0, 0, 0);
  }
  if (colc == 0) {
#pragma unroll
    for (int r = 0; r < 4; r++) {
      sMom[wid * 32 + kg * 4 + r] = m0[r];
      sMom[wid * 32 + 16 + kg * 4 + r] = m1[r];
    }
  }
  __syncthreads();  // all waves done with sYT -> alias as gram
  float* sG = reinterpret_cast<float*>(sYT);  // [4][32][32]
  {
    float* sGw = sG + wid * 1024;
#pragma unroll
    for (int r = 0; r < 4; r++) {
      int rr = kg * 4 + r;
      sGw[rr * 32 + colc] = g00[r];
      sGw[rr * 32 + 16 + colc] = g01[r];
      sGw[(16 + rr) * 32 + 16 + colc] = g11[r];
    }
  }
  __syncthreads();

  float* outp = partials + (size_t)row * NSTAT;
  for (int e = t; e < NSTAT; e += 256) {
    float acc;
    if (e < NPAIR) {
      int ee = e, i = 0;
      while (ee >= (32 - i)) { ee -= (32 - i); i++; }
      int j = i + ee;
      int gi = i * 32 + j;
      acc = sG[gi] + sG[1024 + gi] + sG[2048 + gi] + sG[3072 + gi];
    } else {
      int i = e - NPAIR;
      acc = sMom[i] + sMom[32 + i] + sMom[64 + i] + sMom[96 + i];
    }
    outp[e] = acc;
  }
}

// Reduce partials across the 2048 groups (fp64) -> sred[560]
__global__ __launch_bounds__(256) void nca_reduceA(
    const float* __restrict__ partials, double* __restrict__ sred) {
  __shared__ double red[256];
  int e = blockIdx.x;
  int t = threadIdx.x;
  double acc = 0.0;
  for (int row = t; row < NROW; row += 256)
    acc += (double)partials[(size_t)row * NSTAT + e];
  red[t] = acc;
  __syncthreads();
  for (int s2 = 128; s2 > 0; s2 >>= 1) {
    if (t < s2) red[t] += red[t + s2];
    __syncthreads();
  }
  if (t == 0) sred[e] = red[0];
}

// Per-hid BN constants from moments. fc0_b cancels exactly.
__global__ __launch_bounds__(128) void nca_reduceB(
    const double* __restrict__ sred, const float* __restrict__ fc0w,
    const float* __restrict__ gamma, const float* __restrict__ beta,
    float* __restrict__ ss) {
  __shared__ double S[NSTAT];
  int t = threadIdx.x;
  for (int i = t; i < NSTAT; i += 128) S[i] = sred[i];
  __syncthreads();
  double wv[32];
#pragma unroll
  for (int k = 0; k < 32; k++) wv[k] = (double)fc0w[k * HIDn + t];
  double mean_g = 0.0, q = 0.0;
  int e = 0;
  for (int i = 0; i < 32; i++) {
    mean_g += wv[i] * S[NPAIR + i];
    q += wv[i] * wv[i] * S[e]; e++;
    for (int j = i + 1; j < 32; j++) { q += 2.0 * wv[i] * wv[j] * S[e]; e++; }
  }
  const double invN = 1.0 / (double)NCELLS;
  mean_g *= invN; q *= invN;
  double var = q - mean_g * mean_g;
  double scale = (double)gamma[t] / sqrt(var + 1e-5);
  ss[2 * t]     = (float)scale;
  ss[2 * t + 1] = (float)((double)beta[t] - mean_g * scale);
}

// MFMA update: per wave, 16-cell M-tiles. fc0: 8x mfma_16x16x32_bf16 (K=32);
// BN+relu on f32 accs; repack bf16 via per-wave LDS (XOR swizzle, k-permuted);
// fc1: 4x mfma_16x16x32_bf16 (K=128); residual+mask epilogue.
__global__ __launch_bounds__(256) void nca_update_mfma(
    const float* __restrict__ x, const uint16_t* __restrict__ ybf,
    const uint16_t* __restrict__ w0bf, const uint16_t* __restrict__ w1p,
    const float* __restrict__ ssg, float* __restrict__ xout,
    uint32_t fk0, uint32_t fk1) {
  __shared__ short hbuf[4][16 * 128];  // 4KB per wave
  int t = threadIdx.x;
  int lane = t & 63, wid = t >> 6;
  int col = lane & 15, g = lane >> 4;
  short* hb = hbuf[wid];

  bf16x8 b0[8];
#pragma unroll
  for (int nt = 0; nt < 8; nt++) {
    int n = nt * 16 + col;
    b0[nt] = *reinterpret_cast<const bf16x8*>(w0bf + n * 32 + g * 8);
  }
  bf16x8 b2[4];
#pragma unroll
  for (int kk = 0; kk < 4; kk++)
    b2[kk] = *reinterpret_cast<const bf16x8*>(w1p + col * 128 + kk * 32 + g * 8);
  float sc[8], sh[8];
#pragma unroll
  for (int nt = 0; nt < 8; nt++) {
    float2 v = reinterpret_cast<const float2*>(ssg)[nt * 16 + col];
    sc[nt] = v.x; sh[nt] = v.y;
  }

  uint32_t waveBase = (uint32_t)blockIdx.x * 1024u + (uint32_t)wid * 256u;
  for (int grp = 0; grp < 4; grp++) {
    uint32_t grpBase = waveBase + (uint32_t)grp * 64u;
    float mval = cell_mask(fk0, fk1, grpBase + (uint32_t)lane);
#pragma unroll 1
    for (int tt = 0; tt < 4; tt++) {
      uint32_t tb = grpBase + (uint32_t)tt * 16u;
      bf16x8 a0 = *reinterpret_cast<const bf16x8*>(
          ybf + (size_t)(tb + col) * 32 + g * 8);
      float xv[4];
#pragma unroll
      for (int r = 0; r < 4; r++)
        xv[r] = x[(size_t)(tb + g * 4 + r) * Cn + col];
      f32x4 h[8];
#pragma unroll
      for (int nt = 0; nt < 8; nt++) {
        f32x4 z = {0.f, 0.f, 0.f, 0.f};
        h[nt] = __builtin_amdgcn_mfma_f32_16x16x32_bf16(a0, b0[nt], z, 0, 0, 0);
      }
#pragma unroll
      for (int r = 0; r < 4; r++) {
        int m = g * 4 + r;
        uint32_t u[4];
#pragma unroll
        for (int q = 0; q < 4; q++) {
          float v0 = fmaxf(h[2 * q][r] * sc[2 * q] + sh[2 * q], 0.0f);
          float v1 = fmaxf(h[2 * q + 1][r] * sc[2 * q + 1] + sh[2 * q + 1], 0.0f);
          u[q] = f2bf(v0) | (f2bf(v1) << 16);
        }
        int idx = m * 128 + ((col * 8) ^ ((m & 7) << 3));
        *reinterpret_cast<uint4*>(hb + idx) = make_uint4(u[0], u[1], u[2], u[3]);
      }
      f32x4 dx = {0.f, 0.f, 0.f, 0.f};
#pragma unroll
      for (int kk = 0; kk < 4; kk++) {
        int idx = col * 128 + (((kk * 32) + g * 8) ^ ((col & 7) << 3));
        bf16x8 a2 = *reinterpret_cast<const bf16x8*>(hb + idx);
        dx = __builtin_amdgcn_mfma_f32_16x16x32_bf16(a2, b2[kk], dx, 0, 0, 0);
      }
#pragma unroll
      for (int r = 0; r < 4; r++) {
        int m = g * 4 + r;
        float mk = __shfl(mval, tt * 16 + m);
        float o = xv[r] + dx[r] * mk;
        if (col == 0) o = xv[r];
        xout[(size_t)(tb + m) * Cn + col] = o;
      }
    }
  }
}

extern "C" void kernel_launch(void* const* d_in, const int* in_sizes, int n_in,
                              void* d_out, int out_size, void* d_ws, size_t ws_size,
                              hipStream_t stream) {
  (void)in_sizes; (void)n_in; (void)out_size; (void)ws_size;
  const float* x0    = (const float*)d_in[0];
  const float* p0w   = (const float*)d_in[1];
  const float* p0b   = (const float*)d_in[2];
  const float* fc0w  = (const float*)d_in[3];
  // d_in[4] = fc0_b: cancels exactly in BatchNorm -> unused
  const float* gamma = (const float*)d_in[5];
  const float* beta  = (const float*)d_in[6];
  const float* fc1w  = (const float*)d_in[7];
  // d_in[8] = steps (=10, hardcoded)

  // workspace layout (~72 MB)
  size_t off = 0;
  float* ws_x = (float*)((char*)d_ws + off); off += (size_t)NCELLS * Cn * 4;        // 33.5 MiB
  uint16_t* ws_ybf = (uint16_t*)((char*)d_ws + off); off += (size_t)NCELLS * 32 * 2; // 33.5 MiB
  float* ws_part = (float*)((char*)d_ws + off); off += (size_t)NROW * NSTAT * 4;    // 4.6 MiB
  double* ws_sred = (double*)((char*)d_ws + off); off += (size_t)NSTAT * 8;
  float* ws_ss = (float*)((char*)d_ws + off); off += (size_t)HIDn * 2 * 4;
  uint16_t* ws_w0bf = (uint16_t*)((char*)d_ws + off); off += 4096 * 2;
  uint16_t* ws_w1p = (uint16_t*)((char*)d_ws + off); off += 2048 * 2;
  float* out = (float*)d_out;

  nca_prep<<<24, 256, 0, stream>>>(fc0w, fc1w, ws_w0bf, ws_w1p);

  const float* xin = x0;
  for (int s = 0; s < STEPS; s++) {
    uint32_t fk0 = 0u, fk1 = (uint32_t)s;
    tf2x32(0u, 42u, fk0, fk1);
    float* xo = (((STEPS - 1 - s) & 1) != 0) ? ws_x : out;

    nca_conv<<<Bn * Hn / 2, 256, 0, stream>>>(xin, p0w, p0b, ws_ybf);
    nca_gram<<<NROW, 256, 0, stream>>>(ws_ybf, ws_part);
    nca_reduceA<<<NSTAT, 256, 0, stream>>>(ws_part, ws_sred);
    nca_reduceB<<<1, 128, 0, stream>>>(ws_sred, fc0w, gamma, beta, ws_ss);
    nca_update_mfma<<<NCELLS / 1024, 256, 0, stream>>>(xin, ws_ybf, ws_w0bf,
                                                       ws_w1p, ws_ss, xo, fk0, fk1);
    xin = xo;
  }
}

// Round 9
// 1070.512 us; speedup vs baseline: 18.0959x; 1.0930x over previous
//
#include <hip/hip_runtime.h>
#include <stdint.h>

// BasicNCA2D: 10 steps of depthwise7x7(reflect) -> concat -> fc0 -> BN(batch) -> relu -> fc1 -> masked update.
// B=8,H=256,W=256,C=16,HID=128. steps hardcoded to 10.
// RNG: JAX threefry, jax_threefry_partitionable=True: bits[i] = xor(threefry2x32(key,(0,i))).
//
// R8: nca_conv widened to 4-cell vertical strips (10 rows x 7 dx = 70 loads / 4 cells
// = 17.5 loads/cell vs 28 in R7): more FMA per load + 4 independent acc chains (ILP)
// to cover L1/L2 latency that R7's 31% VALUBusy exposed. dy-loop stays ROLLED (R6's
// full unroll = 256 VGPR + spill). Pack loop fully unrolled (static acc indexing).
// Per-cell tap order (dy,dx) unchanged -> bit-identical output.

constexpr int Bn = 8;
constexpr int Hn = 256;
constexpr int Wn = 256;
constexpr int Cn = 16;
constexpr int HIDn = 128;
constexpr int NROW = Bn * Hn;              // 2048 cell-groups of 256
constexpr int NCELLS = Bn * Hn * Wn;       // 524288
constexpr int NPAIR = 528;                 // 32*33/2 unique second moments of y
constexpr int NSTAT = 560;                 // pairs + 32 first moments
constexpr int STEPS = 10;

typedef __attribute__((ext_vector_type(8))) short bf16x8;
typedef __attribute__((ext_vector_type(4))) float f32x4;

__host__ __device__ inline uint32_t rotl32(uint32_t v, int r) {
  return (v << r) | (v >> (32 - r));
}

// Threefry-2x32, 20 rounds, exactly as jax/_src/prng.py
__host__ __device__ inline void tf2x32(uint32_t k0, uint32_t k1,
                                       uint32_t& x0, uint32_t& x1) {
  uint32_t k2 = k0 ^ k1 ^ 0x1BD11BDAu;
  x0 += k0; x1 += k1;
  x0 += x1; x1 = rotl32(x1, 13); x1 ^= x0;
  x0 += x1; x1 = rotl32(x1, 15); x1 ^= x0;
  x0 += x1; x1 = rotl32(x1, 26); x1 ^= x0;
  x0 += x1; x1 = rotl32(x1,  6); x1 ^= x0;
  x0 += k1; x1 += k2 + 1u;
  x0 += x1; x1 = rotl32(x1, 17); x1 ^= x0;
  x0 += x1; x1 = rotl32(x1, 29); x1 ^= x0;
  x0 += x1; x1 = rotl32(x1, 16); x1 ^= x0;
  x0 += x1; x1 = rotl32(x1, 24); x1 ^= x0;
  x0 += k2; x1 += k0 + 2u;
  x0 += x1; x1 = rotl32(x1, 13); x1 ^= x0;
  x0 += x1; x1 = rotl32(x1, 15); x1 ^= x0;
  x0 += x1; x1 = rotl32(x1, 26); x1 ^= x0;
  x0 += x1; x1 = rotl32(x1,  6); x1 ^= x0;
  x0 += k0; x1 += k1 + 3u;
  x0 += x1; x1 = rotl32(x1, 17); x1 ^= x0;
  x0 += x1; x1 = rotl32(x1, 29); x1 ^= x0;
  x0 += x1; x1 = rotl32(x1, 16); x1 ^= x0;
  x0 += x1; x1 = rotl32(x1, 24); x1 ^= x0;
  x0 += k1; x1 += k2 + 4u;
  x0 += x1; x1 = rotl32(x1, 13); x1 ^= x0;
  x0 += x1; x1 = rotl32(x1, 15); x1 ^= x0;
  x0 += x1; x1 = rotl32(x1, 26); x1 ^= x0;
  x0 += x1; x1 = rotl32(x1,  6); x1 ^= x0;
  x0 += k2; x1 += k0 + 5u;
}

__device__ inline float cell_mask(uint32_t fk0, uint32_t fk1, uint32_t ci) {
  uint32_t a = 0u, b2 = ci;
  tf2x32(fk0, fk1, a, b2);
  uint32_t bits = a ^ b2;
  float u = __uint_as_float((bits >> 9) | 0x3f800000u) - 1.0f;
  return (u > 0.5f) ? 1.0f : 0.0f;
}

// fp32 -> bf16 bits, round-to-nearest-even
__device__ inline uint32_t f2bf(float f) {
  uint32_t u = __float_as_uint(f);
  return (u + 0x7fffu + ((u >> 16) & 1u)) >> 16;
}

// one-time prep:
//  w0bf [n=128][k=32] bf16 : w0bf[n*32+k] = bf16(fc0w[k*128+n])
//  w1p  [c=16][kl=128] bf16: n = (kl&7)*16 + (kl>>3); w1p[c*128+kl] = bf16(fc1w[n*16+c])
__global__ __launch_bounds__(256) void nca_prep(const float* __restrict__ fc0w,
                                                const float* __restrict__ fc1w,
                                                uint16_t* __restrict__ w0bf,
                                                uint16_t* __restrict__ w1p) {
  int i = blockIdx.x * 256 + threadIdx.x;  // 0..6143
  if (i < 4096) {
    int n = i >> 5, k = i & 31;
    w0bf[i] = (uint16_t)f2bf(fc0w[k * HIDn + n]);
  } else {
    int j = i - 4096;
    int c = j >> 7, kl = j & 127;
    int n = (kl & 7) * 16 + (kl >> 3);
    w1p[j] = (uint16_t)f2bf(fc1w[n * 16 + c]);
  }
}

// Conv pass: 4-cell vertical strip per thread, dy-loop ROLLED, dx unrolled.
// Block = (b, h0..h0+3), w = threadIdx. 10 input rows slide once; each loaded
// column feeds up to 4 cells. Writes y=[x|conv+b] bf16 to ybf.
__global__ __launch_bounds__(256, 3) void nca_conv(
    const float* __restrict__ x, const float* __restrict__ p0w,
    const float* __restrict__ p0b, uint16_t* __restrict__ ybf) {
  __shared__ float sW[784];
  __shared__ float sB[16];
  int t = threadIdx.x;
  int bid = blockIdx.x;
  int b = bid & 7;               // one image per XCD
  int h0 = (bid >> 3) * 4;
  for (int i = t; i < 784; i += 256) sW[i] = p0w[i];
  if (t < 16) sB[t] = p0b[t];
  __syncthreads();

  const float* xb = x + (size_t)b * (Hn * Wn * Cn);
  int w = t;
  float acc[4][16];
#pragma unroll
  for (int j = 0; j < 4; j++)
#pragma unroll
    for (int c = 0; c < 16; c++) acc[j][c] = 0.0f;

#pragma unroll 1
  for (int r = 0; r < 10; r++) {
    int hi = h0 - 3 + r;
    hi = (hi < 0) ? -hi : ((hi >= Hn) ? (2 * Hn - 2 - hi) : hi);
    const float* xr = xb + (size_t)hi * (Wn * Cn);
#pragma unroll
    for (int dx = 0; dx < 7; dx++) {
      int ww = w + dx - 3;
      ww = (ww < 0) ? -ww : ((ww >= Wn) ? (2 * Wn - 2 - ww) : ww);
      const float4* p = reinterpret_cast<const float4*>(xr + (size_t)ww * Cn);
      float4 v0 = p[0], v1 = p[1], v2 = p[2], v3 = p[3];
      float v[16];
      v[0] = v0.x;  v[1] = v0.y;  v[2] = v0.z;  v[3] = v0.w;
      v[4] = v1.x;  v[5] = v1.y;  v[6] = v1.z;  v[7] = v1.w;
      v[8] = v2.x;  v[9] = v2.y;  v[10] = v2.z; v[11] = v2.w;
      v[12] = v3.x; v[13] = v3.y; v[14] = v3.z; v[15] = v3.w;
#pragma unroll
      for (int j = 0; j < 4; j++) {
        if (r >= j && r <= j + 6) {  // cell j taps dy = r-j (wave-uniform branch)
          const float* wt = sW + ((r - j) * 7 + dx) * 16;
#pragma unroll
          for (int c = 0; c < 16; c++) acc[j][c] += wt[c] * v[c];
        }
      }
    }
  }

  // pack & store 4 cells (center x reloaded, L1-hot); unrolled -> static acc index
#pragma unroll
  for (int j = 0; j < 4; j++) {
    size_t ci = ((size_t)(b * Hn + h0 + j) * Wn + w);
    const float4* pc = reinterpret_cast<const float4*>(
        xb + ((size_t)(h0 + j) * Wn + w) * Cn);
    float4 c0v = pc[0], c1v = pc[1], c2v = pc[2], c3v = pc[3];
    float xcv[16];
    xcv[0] = c0v.x;  xcv[1] = c0v.y;  xcv[2] = c0v.z;  xcv[3] = c0v.w;
    xcv[4] = c1v.x;  xcv[5] = c1v.y;  xcv[6] = c1v.z;  xcv[7] = c1v.w;
    xcv[8] = c2v.x;  xcv[9] = c2v.y;  xcv[10] = c2v.z; xcv[11] = c2v.w;
    xcv[12] = c3v.x; xcv[13] = c3v.y; xcv[14] = c3v.z; xcv[15] = c3v.w;
    uint32_t pk[16];
#pragma unroll
    for (int q = 0; q < 8; q++)
      pk[q] = f2bf(xcv[2 * q]) | (f2bf(xcv[2 * q + 1]) << 16);
#pragma unroll
    for (int q = 0; q < 8; q++)
      pk[8 + q] = f2bf(acc[j][2 * q] + sB[2 * q]) |
                  (f2bf(acc[j][2 * q + 1] + sB[2 * q + 1]) << 16);
    uint4* yp = reinterpret_cast<uint4*>(ybf + ci * 32);
    yp[0] = make_uint4(pk[0], pk[1], pk[2], pk[3]);
    yp[1] = make_uint4(pk[4], pk[5], pk[6], pk[7]);
    yp[2] = make_uint4(pk[8], pk[9], pk[10], pk[11]);
    yp[3] = make_uint4(pk[12], pk[13], pk[14], pk[15]);
  }
}

// Gram pass: 256 cells/block. Coalesced ybf load -> channel-major swizzled LDS ->
// per-wave 32x32 gram of 64 cells via 6 MFMAs (+4 with B=ones for moments) ->
// block partials [560].
__global__ __launch_bounds__(256) void nca_gram(
    const uint16_t* __restrict__ ybf, float* __restrict__ partials) {
  __shared__ __align__(16) short sYT[32 * 256];  // elem (c,k) at c*256+(k^((c&7)<<3)); aliased as f32 gram[4][1024]
  __shared__ float sMom[4 * 32];
  int t = threadIdx.x;
  int lane = t & 63, wid = t >> 6;
  int row = blockIdx.x;

  const uint4* yp = reinterpret_cast<const uint4*>(ybf + ((size_t)row * 256 + t) * 32);
  uint4 q0 = yp[0], q1 = yp[1], q2 = yp[2], q3 = yp[3];
  uint32_t pk[16] = {q0.x, q0.y, q0.z, q0.w, q1.x, q1.y, q1.z, q1.w,
                     q2.x, q2.y, q2.z, q2.w, q3.x, q3.y, q3.z, q3.w};
#pragma unroll
  for (int c = 0; c < 32; c++) {
    uint16_t hv = (c & 1) ? (uint16_t)(pk[c >> 1] >> 16) : (uint16_t)(pk[c >> 1] & 0xffffu);
    sYT[c * 256 + (t ^ ((c & 7) << 3))] = (short)hv;
  }
  __syncthreads();

  int colc = lane & 15, kg = lane >> 4;
  f32x4 g00 = {0.f, 0.f, 0.f, 0.f}, g01 = g00, g11 = g00, m0 = g00, m1 = g00;
  bf16x8 ones;
#pragma unroll
  for (int e = 0; e < 8; e++) ones[e] = (short)0x3F80;  // bf16 1.0
#pragma unroll
  for (int s2 = 0; s2 < 2; s2++) {
    int kbase = wid * 64 + s2 * 32 + kg * 8;
    int ch0 = colc, ch1 = 16 + colc;
    bf16x8 f0 = *reinterpret_cast<const bf16x8*>(sYT + ch0 * 256 + (kbase ^ ((ch0 & 7) << 3)));
    bf16x8 f1 = *reinterpret_cast<const bf16x8*>(sYT + ch1 * 256 + (kbase ^ ((ch1 & 7) << 3)));
    g00 = __builtin_amdgcn_mfma_f32_16x16x32_bf16(f0, f0, g00, 0, 0, 0);
    g01 = __builtin_amdgcn_mfma_f32_16x16x32_bf16(f0, f1, g01, 0, 0, 0);
    g11 = __builtin_amdgcn_mfma_f32_16x16x32_bf16(f1, f1, g11, 0, 0, 0);
    m0  = __builtin_amdgcn_mfma_f32_16x16x32_bf16(f0, ones, m0, 0, 0, 0);
    m1  = __builtin_amdgcn_mfma_f32_16x16x32_bf16(f1, ones, m1, 0, 0, 0);
  }
  if (colc == 0) {
#pragma unroll
    for (int r = 0; r < 4; r++) {
      sMom[wid * 32 + kg * 4 + r] = m0[r];
      sMom[wid * 32 + 16 + kg * 4 + r] = m1[r];
    }
  }
  __syncthreads();  // all waves done with sYT -> alias as gram
  float* sG = reinterpret_cast<float*>(sYT);  // [4][32][32]
  {
    float* sGw = sG + wid * 1024;
#pragma unroll
    for (int r = 0; r < 4; r++) {
      int rr = kg * 4 + r;
      sGw[rr * 32 + colc] = g00[r];
      sGw[rr * 32 + 16 + colc] = g01[r];
      sGw[(16 + rr) * 32 + 16 + colc] = g11[r];
    }
  }
  __syncthreads();

  float* outp = partials + (size_t)row * NSTAT;
  for (int e = t; e < NSTAT; e += 256) {
    float acc;
    if (e < NPAIR) {
      int ee = e, i = 0;
      while (ee >= (32 - i)) { ee -= (32 - i); i++; }
      int j = i + ee;
      int gi = i * 32 + j;
      acc = sG[gi] + sG[1024 + gi] + sG[2048 + gi] + sG[3072 + gi];
    } else {
      int i = e - NPAIR;
      acc = sMom[i] + sMom[32 + i] + sMom[64 + i] + sMom[96 + i];
    }
    outp[e] = acc;
  }
}

// Reduce partials across the 2048 groups (fp64) -> sred[560]
__global__ __launch_bounds__(256) void nca_reduceA(
    const float* __restrict__ partials, double* __restrict__ sred) {
  __shared__ double red[256];
  int e = blockIdx.x;
  int t = threadIdx.x;
  double acc = 0.0;
  for (int row = t; row < NROW; row += 256)
    acc += (double)partials[(size_t)row * NSTAT + e];
  red[t] = acc;
  __syncthreads();
  for (int s2 = 128; s2 > 0; s2 >>= 1) {
    if (t < s2) red[t] += red[t + s2];
    __syncthreads();
  }
  if (t == 0) sred[e] = red[0];
}

// Per-hid BN constants from moments. fc0_b cancels exactly.
__global__ __launch_bounds__(128) void nca_reduceB(
    const double* __restrict__ sred, const float* __restrict__ fc0w,
    const float* __restrict__ gamma, const float* __restrict__ beta,
    float* __restrict__ ss) {
  __shared__ double S[NSTAT];
  int t = threadIdx.x;
  for (int i = t; i < NSTAT; i += 128) S[i] = sred[i];
  __syncthreads();
  double wv[32];
#pragma unroll
  for (int k = 0; k < 32; k++) wv[k] = (double)fc0w[k * HIDn + t];
  double mean_g = 0.0, q = 0.0;
  int e = 0;
  for (int i = 0; i < 32; i++) {
    mean_g += wv[i] * S[NPAIR + i];
    q += wv[i] * wv[i] * S[e]; e++;
    for (int j = i + 1; j < 32; j++) { q += 2.0 * wv[i] * wv[j] * S[e]; e++; }
  }
  const double invN = 1.0 / (double)NCELLS;
  mean_g *= invN; q *= invN;
  double var = q - mean_g * mean_g;
  double scale = (double)gamma[t] / sqrt(var + 1e-5);
  ss[2 * t]     = (float)scale;
  ss[2 * t + 1] = (float)((double)beta[t] - mean_g * scale);
}

// MFMA update: per wave, 16-cell M-tiles. fc0: 8x mfma_16x16x32_bf16 (K=32);
// BN+relu on f32 accs; repack bf16 via per-wave LDS (XOR swizzle, k-permuted);
// fc1: 4x mfma_16x16x32_bf16 (K=128); residual+mask epilogue.
__global__ __launch_bounds__(256) void nca_update_mfma(
    const float* __restrict__ x, const uint16_t* __restrict__ ybf,
    const uint16_t* __restrict__ w0bf, const uint16_t* __restrict__ w1p,
    const float* __restrict__ ssg, float* __restrict__ xout,
    uint32_t fk0, uint32_t fk1) {
  __shared__ short hbuf[4][16 * 128];  // 4KB per wave
  int t = threadIdx.x;
  int lane = t & 63, wid = t >> 6;
  int col = lane & 15, g = lane >> 4;
  short* hb = hbuf[wid];

  bf16x8 b0[8];
#pragma unroll
  for (int nt = 0; nt < 8; nt++) {
    int n = nt * 16 + col;
    b0[nt] = *reinterpret_cast<const bf16x8*>(w0bf + n * 32 + g * 8);
  }
  bf16x8 b2[4];
#pragma unroll
  for (int kk = 0; kk < 4; kk++)
    b2[kk] = *reinterpret_cast<const bf16x8*>(w1p + col * 128 + kk * 32 + g * 8);
  float sc[8], sh[8];
#pragma unroll
  for (int nt = 0; nt < 8; nt++) {
    float2 v = reinterpret_cast<const float2*>(ssg)[nt * 16 + col];
    sc[nt] = v.x; sh[nt] = v.y;
  }

  uint32_t waveBase = (uint32_t)blockIdx.x * 1024u + (uint32_t)wid * 256u;
  for (int grp = 0; grp < 4; grp++) {
    uint32_t grpBase = waveBase + (uint32_t)grp * 64u;
    float mval = cell_mask(fk0, fk1, grpBase + (uint32_t)lane);
#pragma unroll 1
    for (int tt = 0; tt < 4; tt++) {
      uint32_t tb = grpBase + (uint32_t)tt * 16u;
      bf16x8 a0 = *reinterpret_cast<const bf16x8*>(
          ybf + (size_t)(tb + col) * 32 + g * 8);
      float xv[4];
#pragma unroll
      for (int r = 0; r < 4; r++)
        xv[r] = x[(size_t)(tb + g * 4 + r) * Cn + col];
      f32x4 h[8];
#pragma unroll
      for (int nt = 0; nt < 8; nt++) {
        f32x4 z = {0.f, 0.f, 0.f, 0.f};
        h[nt] = __builtin_amdgcn_mfma_f32_16x16x32_bf16(a0, b0[nt], z, 0, 0, 0);
      }
#pragma unroll
      for (int r = 0; r < 4; r++) {
        int m = g * 4 + r;
        uint32_t u[4];
#pragma unroll
        for (int q = 0; q < 4; q++) {
          float v0 = fmaxf(h[2 * q][r] * sc[2 * q] + sh[2 * q], 0.0f);
          float v1 = fmaxf(h[2 * q + 1][r] * sc[2 * q + 1] + sh[2 * q + 1], 0.0f);
          u[q] = f2bf(v0) | (f2bf(v1) << 16);
        }
        int idx = m * 128 + ((col * 8) ^ ((m & 7) << 3));
        *reinterpret_cast<uint4*>(hb + idx) = make_uint4(u[0], u[1], u[2], u[3]);
      }
      f32x4 dx = {0.f, 0.f, 0.f, 0.f};
#pragma unroll
      for (int kk = 0; kk < 4; kk++) {
        int idx = col * 128 + (((kk * 32) + g * 8) ^ ((col & 7) << 3));
        bf16x8 a2 = *reinterpret_cast<const bf16x8*>(hb + idx);
        dx = __builtin_amdgcn_mfma_f32_16x16x32_bf16(a2, b2[kk], dx, 0, 0, 0);
      }
#pragma unroll
      for (int r = 0; r < 4; r++) {
        int m = g * 4 + r;
        float mk = __shfl(mval, tt * 16 + m);
        float o = xv[r] + dx[r] * mk;
        if (col == 0) o = xv[r];
        xout[(size_t)(tb + m) * Cn + col] = o;
      }
    }
  }
}

extern "C" void kernel_launch(void* const* d_in, const int* in_sizes, int n_in,
                              void* d_out, int out_size, void* d_ws, size_t ws_size,
                              hipStream_t stream) {
  (void)in_sizes; (void)n_in; (void)out_size; (void)ws_size;
  const float* x0    = (const float*)d_in[0];
  const float* p0w   = (const float*)d_in[1];
  const float* p0b   = (const float*)d_in[2];
  const float* fc0w  = (const float*)d_in[3];
  // d_in[4] = fc0_b: cancels exactly in BatchNorm -> unused
  const float* gamma = (const float*)d_in[5];
  const float* beta  = (const float*)d_in[6];
  const float* fc1w  = (const float*)d_in[7];
  // d_in[8] = steps (=10, hardcoded)

  // workspace layout (~72 MB)
  size_t off = 0;
  float* ws_x = (float*)((char*)d_ws + off); off += (size_t)NCELLS * Cn * 4;        // 33.5 MiB
  uint16_t* ws_ybf = (uint16_t*)((char*)d_ws + off); off += (size_t)NCELLS * 32 * 2; // 33.5 MiB
  float* ws_part = (float*)((char*)d_ws + off); off += (size_t)NROW * NSTAT * 4;    // 4.6 MiB
  double* ws_sred = (double*)((char*)d_ws + off); off += (size_t)NSTAT * 8;
  float* ws_ss = (float*)((char*)d_ws + off); off += (size_t)HIDn * 2 * 4;
  uint16_t* ws_w0bf = (uint16_t*)((char*)d_ws + off); off += 4096 * 2;
  uint16_t* ws_w1p = (uint16_t*)((char*)d_ws + off); off += 2048 * 2;
  float* out = (float*)d_out;

  nca_prep<<<24, 256, 0, stream>>>(fc0w, fc1w, ws_w0bf, ws_w1p);

  const float* xin = x0;
  for (int s = 0; s < STEPS; s++) {
    uint32_t fk0 = 0u, fk1 = (uint32_t)s;
    tf2x32(0u, 42u, fk0, fk1);
    float* xo = (((STEPS - 1 - s) & 1) != 0) ? ws_x : out;

    nca_conv<<<Bn * Hn / 4, 256, 0, stream>>>(xin, p0w, p0b, ws_ybf);
    nca_gram<<<NROW, 256, 0, stream>>>(ws_ybf, ws_part);
    nca_reduceA<<<NSTAT, 256, 0, stream>>>(ws_part, ws_sred);
    nca_reduceB<<<1, 128, 0, stream>>>(ws_sred, fc0w, gamma, beta, ws_ss);
    nca_update_mfma<<<NCELLS / 1024, 256, 0, stream>>>(xin, ws_ybf, ws_w0bf,
                                                       ws_w1p, ws_ss, xo, fk0, fk1);
    xin = xo;
  }
}

// Round 10
// 996.143 us; speedup vs baseline: 19.4469x; 1.0747x over previous
//
#include <hip/hip_runtime.h>
#include <stdint.h>

// BasicNCA2D: 10 steps of depthwise7x7(reflect) -> concat -> fc0 -> BN(batch) -> relu -> fc1 -> masked update.
// B=8,H=256,W=256,C=16,HID=128. steps hardcoded to 10.
// RNG: JAX threefry, jax_threefry_partitionable=True: bits[i] = xor(threefry2x32(key,(0,i))).
//
// R9: nca_conv channel-split. R8 was grid-limited (512 blocks = 2 waves/SIMD) and
// latency-bound (VALU 39%). Now each 4-cell strip is computed by 2 threads (8 channels
// each): block = 128 cols x 2 ch-halves, grid 1024 -> 16 waves/CU (2x TLP), per-thread
// FMA halves. Per-channel tap order (dy,dx) unchanged -> bit-identical output.

constexpr int Bn = 8;
constexpr int Hn = 256;
constexpr int Wn = 256;
constexpr int Cn = 16;
constexpr int HIDn = 128;
constexpr int NROW = Bn * Hn;              // 2048 cell-groups of 256
constexpr int NCELLS = Bn * Hn * Wn;       // 524288
constexpr int NPAIR = 528;                 // 32*33/2 unique second moments of y
constexpr int NSTAT = 560;                 // pairs + 32 first moments
constexpr int STEPS = 10;

typedef __attribute__((ext_vector_type(8))) short bf16x8;
typedef __attribute__((ext_vector_type(4))) float f32x4;

__host__ __device__ inline uint32_t rotl32(uint32_t v, int r) {
  return (v << r) | (v >> (32 - r));
}

// Threefry-2x32, 20 rounds, exactly as jax/_src/prng.py
__host__ __device__ inline void tf2x32(uint32_t k0, uint32_t k1,
                                       uint32_t& x0, uint32_t& x1) {
  uint32_t k2 = k0 ^ k1 ^ 0x1BD11BDAu;
  x0 += k0; x1 += k1;
  x0 += x1; x1 = rotl32(x1, 13); x1 ^= x0;
  x0 += x1; x1 = rotl32(x1, 15); x1 ^= x0;
  x0 += x1; x1 = rotl32(x1, 26); x1 ^= x0;
  x0 += x1; x1 = rotl32(x1,  6); x1 ^= x0;
  x0 += k1; x1 += k2 + 1u;
  x0 += x1; x1 = rotl32(x1, 17); x1 ^= x0;
  x0 += x1; x1 = rotl32(x1, 29); x1 ^= x0;
  x0 += x1; x1 = rotl32(x1, 16); x1 ^= x0;
  x0 += x1; x1 = rotl32(x1, 24); x1 ^= x0;
  x0 += k2; x1 += k0 + 2u;
  x0 += x1; x1 = rotl32(x1, 13); x1 ^= x0;
  x0 += x1; x1 = rotl32(x1, 15); x1 ^= x0;
  x0 += x1; x1 = rotl32(x1, 26); x1 ^= x0;
  x0 += x1; x1 = rotl32(x1,  6); x1 ^= x0;
  x0 += k0; x1 += k1 + 3u;
  x0 += x1; x1 = rotl32(x1, 17); x1 ^= x0;
  x0 += x1; x1 = rotl32(x1, 29); x1 ^= x0;
  x0 += x1; x1 = rotl32(x1, 16); x1 ^= x0;
  x0 += x1; x1 = rotl32(x1, 24); x1 ^= x0;
  x0 += k1; x1 += k2 + 4u;
  x0 += x1; x1 = rotl32(x1, 13); x1 ^= x0;
  x0 += x1; x1 = rotl32(x1, 15); x1 ^= x0;
  x0 += x1; x1 = rotl32(x1, 26); x1 ^= x0;
  x0 += x1; x1 = rotl32(x1,  6); x1 ^= x0;
  x0 += k2; x1 += k0 + 5u;
}

__device__ inline float cell_mask(uint32_t fk0, uint32_t fk1, uint32_t ci) {
  uint32_t a = 0u, b2 = ci;
  tf2x32(fk0, fk1, a, b2);
  uint32_t bits = a ^ b2;
  float u = __uint_as_float((bits >> 9) | 0x3f800000u) - 1.0f;
  return (u > 0.5f) ? 1.0f : 0.0f;
}

// fp32 -> bf16 bits, round-to-nearest-even
__device__ inline uint32_t f2bf(float f) {
  uint32_t u = __float_as_uint(f);
  return (u + 0x7fffu + ((u >> 16) & 1u)) >> 16;
}

// one-time prep:
//  w0bf [n=128][k=32] bf16 : w0bf[n*32+k] = bf16(fc0w[k*128+n])
//  w1p  [c=16][kl=128] bf16: n = (kl&7)*16 + (kl>>3); w1p[c*128+kl] = bf16(fc1w[n*16+c])
__global__ __launch_bounds__(256) void nca_prep(const float* __restrict__ fc0w,
                                                const float* __restrict__ fc1w,
                                                uint16_t* __restrict__ w0bf,
                                                uint16_t* __restrict__ w1p) {
  int i = blockIdx.x * 256 + threadIdx.x;  // 0..6143
  if (i < 4096) {
    int n = i >> 5, k = i & 31;
    w0bf[i] = (uint16_t)f2bf(fc0w[k * HIDn + n]);
  } else {
    int j = i - 4096;
    int c = j >> 7, kl = j & 127;
    int n = (kl & 7) * 16 + (kl >> 3);
    w1p[j] = (uint16_t)f2bf(fc1w[n * 16 + c]);
  }
}

// Conv pass: 4-cell vertical strip, channel-split (2 threads/strip, 8 ch each).
// Block = (b, h-strip, w-half): 128 cols x 2 ch-halves = 256 threads. dy-loop
// ROLLED, dx unrolled. Writes y=[x|conv+b] bf16 halves to ybf.
__global__ __launch_bounds__(256, 4) void nca_conv(
    const float* __restrict__ x, const float* __restrict__ p0w,
    const float* __restrict__ p0b, uint16_t* __restrict__ ybf) {
  __shared__ float sW[784];
  __shared__ float sB[16];
  int t = threadIdx.x;
  int bid = blockIdx.x;
  int b = bid & 7;               // one image per XCD
  int rest = bid >> 3;           // 0..127
  int h0 = (rest >> 1) * 4;
  int wbase = (rest & 1) * 128;
  for (int i = t; i < 784; i += 256) sW[i] = p0w[i];
  if (t < 16) sB[t] = p0b[t];
  __syncthreads();

  int wl = t & 127;
  int ch0 = (t >> 7) * 8;        // 0 or 8
  int w = wbase + wl;
  const float* xb = x + (size_t)b * (Hn * Wn * Cn) + ch0;
  float acc[4][8];
#pragma unroll
  for (int j = 0; j < 4; j++)
#pragma unroll
    for (int c = 0; c < 8; c++) acc[j][c] = 0.0f;

#pragma unroll 1
  for (int r = 0; r < 10; r++) {
    int hi = h0 - 3 + r;
    hi = (hi < 0) ? -hi : ((hi >= Hn) ? (2 * Hn - 2 - hi) : hi);
    const float* xr = xb + (size_t)hi * (Wn * Cn);
#pragma unroll
    for (int dx = 0; dx < 7; dx++) {
      int ww = w + dx - 3;
      ww = (ww < 0) ? -ww : ((ww >= Wn) ? (2 * Wn - 2 - ww) : ww);
      const float4* p = reinterpret_cast<const float4*>(xr + (size_t)ww * Cn);
      float4 v0 = p[0], v1 = p[1];
      float v[8];
      v[0] = v0.x; v[1] = v0.y; v[2] = v0.z; v[3] = v0.w;
      v[4] = v1.x; v[5] = v1.y; v[6] = v1.z; v[7] = v1.w;
#pragma unroll
      for (int j = 0; j < 4; j++) {
        if (r >= j && r <= j + 6) {  // cell j taps dy = r-j (wave-uniform branch)
          const float* wt = sW + ((r - j) * 7 + dx) * 16 + ch0;
#pragma unroll
          for (int c = 0; c < 8; c++) acc[j][c] += wt[c] * v[c];
        }
      }
    }
  }

  // pack & store 4 cells' halves (center x reloaded, L1-hot)
#pragma unroll
  for (int j = 0; j < 4; j++) {
    size_t ci = ((size_t)(b * Hn + h0 + j) * Wn + w);
    const float4* pc = reinterpret_cast<const float4*>(
        xb + ((size_t)(h0 + j) * Wn + w) * Cn);
    float4 c0v = pc[0], c1v = pc[1];
    float xcv[8];
    xcv[0] = c0v.x; xcv[1] = c0v.y; xcv[2] = c0v.z; xcv[3] = c0v.w;
    xcv[4] = c1v.x; xcv[5] = c1v.y; xcv[6] = c1v.z; xcv[7] = c1v.w;
    uint32_t pkx[4], pkc[4];
#pragma unroll
    for (int q = 0; q < 4; q++)
      pkx[q] = f2bf(xcv[2 * q]) | (f2bf(xcv[2 * q + 1]) << 16);
#pragma unroll
    for (int q = 0; q < 4; q++)
      pkc[q] = f2bf(acc[j][2 * q] + sB[ch0 + 2 * q]) |
               (f2bf(acc[j][2 * q + 1] + sB[ch0 + 2 * q + 1]) << 16);
    *reinterpret_cast<uint4*>(ybf + ci * 32 + ch0) =
        make_uint4(pkx[0], pkx[1], pkx[2], pkx[3]);
    *reinterpret_cast<uint4*>(ybf + ci * 32 + 16 + ch0) =
        make_uint4(pkc[0], pkc[1], pkc[2], pkc[3]);
  }
}

// Gram pass: 256 cells/block. Coalesced ybf load -> channel-major swizzled LDS ->
// per-wave 32x32 gram of 64 cells via 6 MFMAs (+4 with B=ones for moments) ->
// block partials [560].
__global__ __launch_bounds__(256) void nca_gram(
    const uint16_t* __restrict__ ybf, float* __restrict__ partials) {
  __shared__ __align__(16) short sYT[32 * 256];  // elem (c,k) at c*256+(k^((c&7)<<3)); aliased as f32 gram[4][1024]
  __shared__ float sMom[4 * 32];
  int t = threadIdx.x;
  int lane = t & 63, wid = t >> 6;
  int row = blockIdx.x;

  const uint4* yp = reinterpret_cast<const uint4*>(ybf + ((size_t)row * 256 + t) * 32);
  uint4 q0 = yp[0], q1 = yp[1], q2 = yp[2], q3 = yp[3];
  uint32_t pk[16] = {q0.x, q0.y, q0.z, q0.w, q1.x, q1.y, q1.z, q1.w,
                     q2.x, q2.y, q2.z, q2.w, q3.x, q3.y, q3.z, q3.w};
#pragma unroll
  for (int c = 0; c < 32; c++) {
    uint16_t hv = (c & 1) ? (uint16_t)(pk[c >> 1] >> 16) : (uint16_t)(pk[c >> 1] & 0xffffu);
    sYT[c * 256 + (t ^ ((c & 7) << 3))] = (short)hv;
  }
  __syncthreads();

  int colc = lane & 15, kg = lane >> 4;
  f32x4 g00 = {0.f, 0.f, 0.f, 0.f}, g01 = g00, g11 = g00, m0 = g00, m1 = g00;
  bf16x8 ones;
#pragma unroll
  for (int e = 0; e < 8; e++) ones[e] = (short)0x3F80;  // bf16 1.0
#pragma unroll
  for (int s2 = 0; s2 < 2; s2++) {
    int kbase = wid * 64 + s2 * 32 + kg * 8;
    int ch0 = colc, ch1 = 16 + colc;
    bf16x8 f0 = *reinterpret_cast<const bf16x8*>(sYT + ch0 * 256 + (kbase ^ ((ch0 & 7) << 3)));
    bf16x8 f1 = *reinterpret_cast<const bf16x8*>(sYT + ch1 * 256 + (kbase ^ ((ch1 & 7) << 3)));
    g00 = __builtin_amdgcn_mfma_f32_16x16x32_bf16(f0, f0, g00, 0, 0, 0);
    g01 = __builtin_amdgcn_mfma_f32_16x16x32_bf16(f0, f1, g01, 0, 0, 0);
    g11 = __builtin_amdgcn_mfma_f32_16x16x32_bf16(f1, f1, g11, 0, 0, 0);
    m0  = __builtin_amdgcn_mfma_f32_16x16x32_bf16(f0, ones, m0, 0, 0, 0);
    m1  = __builtin_amdgcn_mfma_f32_16x16x32_bf16(f1, ones, m1, 0, 0, 0);
  }
  if (colc == 0) {
#pragma unroll
    for (int r = 0; r < 4; r++) {
      sMom[wid * 32 + kg * 4 + r] = m0[r];
      sMom[wid * 32 + 16 + kg * 4 + r] = m1[r];
    }
  }
  __syncthreads();  // all waves done with sYT -> alias as gram
  float* sG = reinterpret_cast<float*>(sYT);  // [4][32][32]
  {
    float* sGw = sG + wid * 1024;
#pragma unroll
    for (int r = 0; r < 4; r++) {
      int rr = kg * 4 + r;
      sGw[rr * 32 + colc] = g00[r];
      sGw[rr * 32 + 16 + colc] = g01[r];
      sGw[(16 + rr) * 32 + 16 + colc] = g11[r];
    }
  }
  __syncthreads();

  float* outp = partials + (size_t)row * NSTAT;
  for (int e = t; e < NSTAT; e += 256) {
    float acc;
    if (e < NPAIR) {
      int ee = e, i = 0;
      while (ee >= (32 - i)) { ee -= (32 - i); i++; }
      int j = i + ee;
      int gi = i * 32 + j;
      acc = sG[gi] + sG[1024 + gi] + sG[2048 + gi] + sG[3072 + gi];
    } else {
      int i = e - NPAIR;
      acc = sMom[i] + sMom[32 + i] + sMom[64 + i] + sMom[96 + i];
    }
    outp[e] = acc;
  }
}

// Reduce partials across the 2048 groups (fp64) -> sred[560]
__global__ __launch_bounds__(256) void nca_reduceA(
    const float* __restrict__ partials, double* __restrict__ sred) {
  __shared__ double red[256];
  int e = blockIdx.x;
  int t = threadIdx.x;
  double acc = 0.0;
  for (int row = t; row < NROW; row += 256)
    acc += (double)partials[(size_t)row * NSTAT + e];
  red[t] = acc;
  __syncthreads();
  for (int s2 = 128; s2 > 0; s2 >>= 1) {
    if (t < s2) red[t] += red[t + s2];
    __syncthreads();
  }
  if (t == 0) sred[e] = red[0];
}

// Per-hid BN constants from moments. fc0_b cancels exactly.
__global__ __launch_bounds__(128) void nca_reduceB(
    const double* __restrict__ sred, const float* __restrict__ fc0w,
    const float* __restrict__ gamma, const float* __restrict__ beta,
    float* __restrict__ ss) {
  __shared__ double S[NSTAT];
  int t = threadIdx.x;
  for (int i = t; i < NSTAT; i += 128) S[i] = sred[i];
  __syncthreads();
  double wv[32];
#pragma unroll
  for (int k = 0; k < 32; k++) wv[k] = (double)fc0w[k * HIDn + t];
  double mean_g = 0.0, q = 0.0;
  int e = 0;
  for (int i = 0; i < 32; i++) {
    mean_g += wv[i] * S[NPAIR + i];
    q += wv[i] * wv[i] * S[e]; e++;
    for (int j = i + 1; j < 32; j++) { q += 2.0 * wv[i] * wv[j] * S[e]; e++; }
  }
  const double invN = 1.0 / (double)NCELLS;
  mean_g *= invN; q *= invN;
  double var = q - mean_g * mean_g;
  double scale = (double)gamma[t] / sqrt(var + 1e-5);
  ss[2 * t]     = (float)scale;
  ss[2 * t + 1] = (float)((double)beta[t] - mean_g * scale);
}

// MFMA update: per wave, 16-cell M-tiles. fc0: 8x mfma_16x16x32_bf16 (K=32);
// BN+relu on f32 accs; repack bf16 via per-wave LDS (XOR swizzle, k-permuted);
// fc1: 4x mfma_16x16x32_bf16 (K=128); residual+mask epilogue.
__global__ __launch_bounds__(256) void nca_update_mfma(
    const float* __restrict__ x, const uint16_t* __restrict__ ybf,
    const uint16_t* __restrict__ w0bf, const uint16_t* __restrict__ w1p,
    const float* __restrict__ ssg, float* __restrict__ xout,
    uint32_t fk0, uint32_t fk1) {
  __shared__ short hbuf[4][16 * 128];  // 4KB per wave
  int t = threadIdx.x;
  int lane = t & 63, wid = t >> 6;
  int col = lane & 15, g = lane >> 4;
  short* hb = hbuf[wid];

  bf16x8 b0[8];
#pragma unroll
  for (int nt = 0; nt < 8; nt++) {
    int n = nt * 16 + col;
    b0[nt] = *reinterpret_cast<const bf16x8*>(w0bf + n * 32 + g * 8);
  }
  bf16x8 b2[4];
#pragma unroll
  for (int kk = 0; kk < 4; kk++)
    b2[kk] = *reinterpret_cast<const bf16x8*>(w1p + col * 128 + kk * 32 + g * 8);
  float sc[8], sh[8];
#pragma unroll
  for (int nt = 0; nt < 8; nt++) {
    float2 v = reinterpret_cast<const float2*>(ssg)[nt * 16 + col];
    sc[nt] = v.x; sh[nt] = v.y;
  }

  uint32_t waveBase = (uint32_t)blockIdx.x * 1024u + (uint32_t)wid * 256u;
  for (int grp = 0; grp < 4; grp++) {
    uint32_t grpBase = waveBase + (uint32_t)grp * 64u;
    float mval = cell_mask(fk0, fk1, grpBase + (uint32_t)lane);
#pragma unroll 1
    for (int tt = 0; tt < 4; tt++) {
      uint32_t tb = grpBase + (uint32_t)tt * 16u;
      bf16x8 a0 = *reinterpret_cast<const bf16x8*>(
          ybf + (size_t)(tb + col) * 32 + g * 8);
      float xv[4];
#pragma unroll
      for (int r = 0; r < 4; r++)
        xv[r] = x[(size_t)(tb + g * 4 + r) * Cn + col];
      f32x4 h[8];
#pragma unroll
      for (int nt = 0; nt < 8; nt++) {
        f32x4 z = {0.f, 0.f, 0.f, 0.f};
        h[nt] = __builtin_amdgcn_mfma_f32_16x16x32_bf16(a0, b0[nt], z, 0, 0, 0);
      }
#pragma unroll
      for (int r = 0; r < 4; r++) {
        int m = g * 4 + r;
        uint32_t u[4];
#pragma unroll
        for (int q = 0; q < 4; q++) {
          float v0 = fmaxf(h[2 * q][r] * sc[2 * q] + sh[2 * q], 0.0f);
          float v1 = fmaxf(h[2 * q + 1][r] * sc[2 * q + 1] + sh[2 * q + 1], 0.0f);
          u[q] = f2bf(v0) | (f2bf(v1) << 16);
        }
        int idx = m * 128 + ((col * 8) ^ ((m & 7) << 3));
        *reinterpret_cast<uint4*>(hb + idx) = make_uint4(u[0], u[1], u[2], u[3]);
      }
      f32x4 dx = {0.f, 0.f, 0.f, 0.f};
#pragma unroll
      for (int kk = 0; kk < 4; kk++) {
        int idx = col * 128 + (((kk * 32) + g * 8) ^ ((col & 7) << 3));
        bf16x8 a2 = *reinterpret_cast<const bf16x8*>(hb + idx);
        dx = __builtin_amdgcn_mfma_f32_16x16x32_bf16(a2, b2[kk], dx, 0, 0, 0);
      }
#pragma unroll
      for (int r = 0; r < 4; r++) {
        int m = g * 4 + r;
        float mk = __shfl(mval, tt * 16 + m);
        float o = xv[r] + dx[r] * mk;
        if (col == 0) o = xv[r];
        xout[(size_t)(tb + m) * Cn + col] = o;
      }
    }
  }
}

extern "C" void kernel_launch(void* const* d_in, const int* in_sizes, int n_in,
                              void* d_out, int out_size, void* d_ws, size_t ws_size,
                              hipStream_t stream) {
  (void)in_sizes; (void)n_in; (void)out_size; (void)ws_size;
  const float* x0    = (const float*)d_in[0];
  const float* p0w   = (const float*)d_in[1];
  const float* p0b   = (const float*)d_in[2];
  const float* fc0w  = (const float*)d_in[3];
  // d_in[4] = fc0_b: cancels exactly in BatchNorm -> unused
  const float* gamma = (const float*)d_in[5];
  const float* beta  = (const float*)d_in[6];
  const float* fc1w  = (const float*)d_in[7];
  // d_in[8] = steps (=10, hardcoded)

  // workspace layout (~72 MB)
  size_t off = 0;
  float* ws_x = (float*)((char*)d_ws + off); off += (size_t)NCELLS * Cn * 4;        // 33.5 MiB
  uint16_t* ws_ybf = (uint16_t*)((char*)d_ws + off); off += (size_t)NCELLS * 32 * 2; // 33.5 MiB
  float* ws_part = (float*)((char*)d_ws + off); off += (size_t)NROW * NSTAT * 4;    // 4.6 MiB
  double* ws_sred = (double*)((char*)d_ws + off); off += (size_t)NSTAT * 8;
  float* ws_ss = (float*)((char*)d_ws + off); off += (size_t)HIDn * 2 * 4;
  uint16_t* ws_w0bf = (uint16_t*)((char*)d_ws + off); off += 4096 * 2;
  uint16_t* ws_w1p = (uint16_t*)((char*)d_ws + off); off += 2048 * 2;
  float* out = (float*)d_out;

  nca_prep<<<24, 256, 0, stream>>>(fc0w, fc1w, ws_w0bf, ws_w1p);

  const float* xin = x0;
  for (int s = 0; s < STEPS; s++) {
    uint32_t fk0 = 0u, fk1 = (uint32_t)s;
    tf2x32(0u, 42u, fk0, fk1);
    float* xo = (((STEPS - 1 - s) & 1) != 0) ? ws_x : out;

    nca_conv<<<Bn * Hn / 4 * 2, 256, 0, stream>>>(xin, p0w, p0b, ws_ybf);
    nca_gram<<<NROW, 256, 0, stream>>>(ws_ybf, ws_part);
    nca_reduceA<<<NSTAT, 256, 0, stream>>>(ws_part, ws_sred);
    nca_reduceB<<<1, 128, 0, stream>>>(ws_sred, fc0w, gamma, beta, ws_ss);
    nca_update_mfma<<<NCELLS / 1024, 256, 0, stream>>>(xin, ws_ybf, ws_w0bf,
                                                       ws_w1p, ws_ss, xo, fk0, fk1);
    xin = xo;
  }
}

// Round 11
// 877.326 us; speedup vs baseline: 22.0806x; 1.1354x over previous
//
#include <hip/hip_runtime.h>
#include <stdint.h>

// BasicNCA2D: 10 steps of depthwise7x7(reflect) -> concat -> fc0 -> BN(batch) -> relu -> fc1 -> masked update.
// B=8,H=256,W=256,C=16,HID=128. steps hardcoded to 10.
// RNG: JAX threefry, jax_threefry_partitionable=True: bits[i] = xor(threefry2x32(key,(0,i))).
//
// R10: gram fused into conv (nca_convgram). The separate gram kernel's cost was
// re-reading the 33.5MB ybf conv just wrote; conv is latency-bound (VALU 44%), so the
// gram's DS-transpose + 20 MFMAs/wave ride on idle pipes (R4 lesson, deliberately).
// Block = 512 cells (4 rows x 128 cols, both ch-halves); y bf16 -> 32KB LDS channel-major
// (XOR swizzle); per-wave 32x32 gram over 128 cells (4 k-iters x 5 MFMAs, verified R5
// structure); partials [1024][560]. reduceA row count 2048 -> 1024.

constexpr int Bn = 8;
constexpr int Hn = 256;
constexpr int Wn = 256;
constexpr int Cn = 16;
constexpr int HIDn = 128;
constexpr int NCELLS = Bn * Hn * Wn;       // 524288
constexpr int NGRP = 1024;                 // fused conv+gram blocks (512 cells each)
constexpr int NPAIR = 528;                 // 32*33/2 unique second moments of y
constexpr int NSTAT = 560;                 // pairs + 32 first moments
constexpr int STEPS = 10;

typedef __attribute__((ext_vector_type(8))) short bf16x8;
typedef __attribute__((ext_vector_type(4))) float f32x4;

__host__ __device__ inline uint32_t rotl32(uint32_t v, int r) {
  return (v << r) | (v >> (32 - r));
}

// Threefry-2x32, 20 rounds, exactly as jax/_src/prng.py
__host__ __device__ inline void tf2x32(uint32_t k0, uint32_t k1,
                                       uint32_t& x0, uint32_t& x1) {
  uint32_t k2 = k0 ^ k1 ^ 0x1BD11BDAu;
  x0 += k0; x1 += k1;
  x0 += x1; x1 = rotl32(x1, 13); x1 ^= x0;
  x0 += x1; x1 = rotl32(x1, 15); x1 ^= x0;
  x0 += x1; x1 = rotl32(x1, 26); x1 ^= x0;
  x0 += x1; x1 = rotl32(x1,  6); x1 ^= x0;
  x0 += k1; x1 += k2 + 1u;
  x0 += x1; x1 = rotl32(x1, 17); x1 ^= x0;
  x0 += x1; x1 = rotl32(x1, 29); x1 ^= x0;
  x0 += x1; x1 = rotl32(x1, 16); x1 ^= x0;
  x0 += x1; x1 = rotl32(x1, 24); x1 ^= x0;
  x0 += k2; x1 += k0 + 2u;
  x0 += x1; x1 = rotl32(x1, 13); x1 ^= x0;
  x0 += x1; x1 = rotl32(x1, 15); x1 ^= x0;
  x0 += x1; x1 = rotl32(x1, 26); x1 ^= x0;
  x0 += x1; x1 = rotl32(x1,  6); x1 ^= x0;
  x0 += k0; x1 += k1 + 3u;
  x0 += x1; x1 = rotl32(x1, 17); x1 ^= x0;
  x0 += x1; x1 = rotl32(x1, 29); x1 ^= x0;
  x0 += x1; x1 = rotl32(x1, 16); x1 ^= x0;
  x0 += x1; x1 = rotl32(x1, 24); x1 ^= x0;
  x0 += k1; x1 += k2 + 4u;
  x0 += x1; x1 = rotl32(x1, 13); x1 ^= x0;
  x0 += x1; x1 = rotl32(x1, 15); x1 ^= x0;
  x0 += x1; x1 = rotl32(x1, 26); x1 ^= x0;
  x0 += x1; x1 = rotl32(x1,  6); x1 ^= x0;
  x0 += k2; x1 += k0 + 5u;
}

__device__ inline float cell_mask(uint32_t fk0, uint32_t fk1, uint32_t ci) {
  uint32_t a = 0u, b2 = ci;
  tf2x32(fk0, fk1, a, b2);
  uint32_t bits = a ^ b2;
  float u = __uint_as_float((bits >> 9) | 0x3f800000u) - 1.0f;
  return (u > 0.5f) ? 1.0f : 0.0f;
}

// fp32 -> bf16 bits, round-to-nearest-even
__device__ inline uint32_t f2bf(float f) {
  uint32_t u = __float_as_uint(f);
  return (u + 0x7fffu + ((u >> 16) & 1u)) >> 16;
}

// one-time prep:
//  w0bf [n=128][k=32] bf16 : w0bf[n*32+k] = bf16(fc0w[k*128+n])
//  w1p  [c=16][kl=128] bf16: n = (kl&7)*16 + (kl>>3); w1p[c*128+kl] = bf16(fc1w[n*16+c])
__global__ __launch_bounds__(256) void nca_prep(const float* __restrict__ fc0w,
                                                const float* __restrict__ fc1w,
                                                uint16_t* __restrict__ w0bf,
                                                uint16_t* __restrict__ w1p) {
  int i = blockIdx.x * 256 + threadIdx.x;  // 0..6143
  if (i < 4096) {
    int n = i >> 5, k = i & 31;
    w0bf[i] = (uint16_t)f2bf(fc0w[k * HIDn + n]);
  } else {
    int j = i - 4096;
    int c = j >> 7, kl = j & 127;
    int n = (kl & 7) * 16 + (kl >> 3);
    w1p[j] = (uint16_t)f2bf(fc1w[n * 16 + c]);
  }
}

// Fused conv+gram. Block = (b, h-strip of 4, w-half of 128): 512 cells, 256 threads
// (128 cols x 2 ch-halves, 8 ch each). Conv: 4-cell strips, dy ROLLED, dx unrolled
// (R9 codegen). Then y bf16 -> LDS channel-major (swizzled), barrier, per-wave 32x32
// gram over 128 cells via MFMA (+ B=ones moments), partials[1024][560].
__global__ __launch_bounds__(256, 4) void nca_convgram(
    const float* __restrict__ x, const float* __restrict__ p0w,
    const float* __restrict__ p0b, uint16_t* __restrict__ ybf,
    float* __restrict__ partials) {
  __shared__ float sW[784];
  __shared__ float sB[16];
  __shared__ __align__(16) short sYT[32 * 512];  // (c,k) at c*512+(k^((c&7)<<3)); aliased later as f32 gram[4][1024]
  __shared__ float sMom[4 * 32];
  int t = threadIdx.x;
  int lane = t & 63, wid = t >> 6;
  int bid = blockIdx.x;
  int b = bid & 7;               // one image per XCD
  int rest = bid >> 3;           // 0..127
  int h0 = (rest >> 1) * 4;
  int wbase = (rest & 1) * 128;
  for (int i = t; i < 784; i += 256) sW[i] = p0w[i];
  if (t < 16) sB[t] = p0b[t];
  __syncthreads();

  int wl = t & 127;
  int ch0 = (t >> 7) * 8;        // 0 or 8
  int w = wbase + wl;
  const float* xb = x + (size_t)b * (Hn * Wn * Cn) + ch0;
  float acc[4][8];
#pragma unroll
  for (int j = 0; j < 4; j++)
#pragma unroll
    for (int c = 0; c < 8; c++) acc[j][c] = 0.0f;

#pragma unroll 1
  for (int r = 0; r < 10; r++) {
    int hi = h0 - 3 + r;
    hi = (hi < 0) ? -hi : ((hi >= Hn) ? (2 * Hn - 2 - hi) : hi);
    const float* xr = xb + (size_t)hi * (Wn * Cn);
#pragma unroll
    for (int dx = 0; dx < 7; dx++) {
      int ww = w + dx - 3;
      ww = (ww < 0) ? -ww : ((ww >= Wn) ? (2 * Wn - 2 - ww) : ww);
      const float4* p = reinterpret_cast<const float4*>(xr + (size_t)ww * Cn);
      float4 v0 = p[0], v1 = p[1];
      float v[8];
      v[0] = v0.x; v[1] = v0.y; v[2] = v0.z; v[3] = v0.w;
      v[4] = v1.x; v[5] = v1.y; v[6] = v1.z; v[7] = v1.w;
#pragma unroll
      for (int j = 0; j < 4; j++) {
        if (r >= j && r <= j + 6) {  // cell j taps dy = r-j (wave-uniform branch)
          const float* wt = sW + ((r - j) * 7 + dx) * 16 + ch0;
#pragma unroll
          for (int c = 0; c < 8; c++) acc[j][c] += wt[c] * v[c];
        }
      }
    }
  }

  // pack & store 4 cells' halves to global ybf + LDS channel-major (swizzled)
#pragma unroll
  for (int j = 0; j < 4; j++) {
    size_t ci = ((size_t)(b * Hn + h0 + j) * Wn + w);
    int cidx = j * 128 + wl;     // cell index within block [0,512)
    const float4* pc = reinterpret_cast<const float4*>(
        xb + ((size_t)(h0 + j) * Wn + w) * Cn);
    float4 c0v = pc[0], c1v = pc[1];
    float xcv[8];
    xcv[0] = c0v.x; xcv[1] = c0v.y; xcv[2] = c0v.z; xcv[3] = c0v.w;
    xcv[4] = c1v.x; xcv[5] = c1v.y; xcv[6] = c1v.z; xcv[7] = c1v.w;
    uint32_t pkx[4], pkc[4];
#pragma unroll
    for (int q = 0; q < 4; q++)
      pkx[q] = f2bf(xcv[2 * q]) | (f2bf(xcv[2 * q + 1]) << 16);
#pragma unroll
    for (int q = 0; q < 4; q++)
      pkc[q] = f2bf(acc[j][2 * q] + sB[ch0 + 2 * q]) |
               (f2bf(acc[j][2 * q + 1] + sB[ch0 + 2 * q + 1]) << 16);
    *reinterpret_cast<uint4*>(ybf + ci * 32 + ch0) =
        make_uint4(pkx[0], pkx[1], pkx[2], pkx[3]);
    *reinterpret_cast<uint4*>(ybf + ci * 32 + 16 + ch0) =
        make_uint4(pkc[0], pkc[1], pkc[2], pkc[3]);
    // LDS transpose: x half -> channels ch0..ch0+7, conv half -> 16+ch0..
#pragma unroll
    for (int q = 0; q < 4; q++) {
      int cA = ch0 + 2 * q, cB = cA + 1;
      sYT[cA * 512 + (cidx ^ ((cA & 7) << 3))] = (short)(uint16_t)(pkx[q] & 0xffffu);
      sYT[cB * 512 + (cidx ^ ((cB & 7) << 3))] = (short)(uint16_t)(pkx[q] >> 16);
      int cC = 16 + cA, cD = 16 + cB;
      sYT[cC * 512 + (cidx ^ ((cC & 7) << 3))] = (short)(uint16_t)(pkc[q] & 0xffffu);
      sYT[cD * 512 + (cidx ^ ((cD & 7) << 3))] = (short)(uint16_t)(pkc[q] >> 16);
    }
  }
  __syncthreads();

  // per-wave gram over cells [wid*128, wid*128+128)
  int colc = lane & 15, kg = lane >> 4;
  f32x4 g00 = {0.f, 0.f, 0.f, 0.f}, g01 = g00, g11 = g00, m0 = g00, m1 = g00;
  bf16x8 ones;
#pragma unroll
  for (int e = 0; e < 8; e++) ones[e] = (short)0x3F80;  // bf16 1.0
#pragma unroll
  for (int s2 = 0; s2 < 4; s2++) {
    int kbase = wid * 128 + s2 * 32 + kg * 8;
    int chA = colc, chB = 16 + colc;
    bf16x8 f0 = *reinterpret_cast<const bf16x8*>(sYT + chA * 512 + (kbase ^ ((chA & 7) << 3)));
    bf16x8 f1 = *reinterpret_cast<const bf16x8*>(sYT + chB * 512 + (kbase ^ ((chB & 7) << 3)));
    g00 = __builtin_amdgcn_mfma_f32_16x16x32_bf16(f0, f0, g00, 0, 0, 0);
    g01 = __builtin_amdgcn_mfma_f32_16x16x32_bf16(f0, f1, g01, 0, 0, 0);
    g11 = __builtin_amdgcn_mfma_f32_16x16x32_bf16(f1, f1, g11, 0, 0, 0);
    m0  = __builtin_amdgcn_mfma_f32_16x16x32_bf16(f0, ones, m0, 0, 0, 0);
    m1  = __builtin_amdgcn_mfma_f32_16x16x32_bf16(f1, ones, m1, 0, 0, 0);
  }
  if (colc == 0) {
#pragma unroll
    for (int r = 0; r < 4; r++) {
      sMom[wid * 32 + kg * 4 + r] = m0[r];
      sMom[wid * 32 + 16 + kg * 4 + r] = m1[r];
    }
  }
  __syncthreads();  // all waves done reading sYT -> safe to alias as gram
  float* sG = reinterpret_cast<float*>(sYT);  // [4][32][32]
  {
    float* sGw = sG + wid * 1024;
#pragma unroll
    for (int r = 0; r < 4; r++) {
      int rr = kg * 4 + r;
      sGw[rr * 32 + colc] = g00[r];
      sGw[rr * 32 + 16 + colc] = g01[r];
      sGw[(16 + rr) * 32 + 16 + colc] = g11[r];
    }
  }
  __syncthreads();

  float* outp = partials + (size_t)bid * NSTAT;
  for (int e = t; e < NSTAT; e += 256) {
    float a;
    if (e < NPAIR) {
      int ee = e, i = 0;
      while (ee >= (32 - i)) { ee -= (32 - i); i++; }
      int j = i + ee;
      int gi = i * 32 + j;
      a = sG[gi] + sG[1024 + gi] + sG[2048 + gi] + sG[3072 + gi];
    } else {
      int i = e - NPAIR;
      a = sMom[i] + sMom[32 + i] + sMom[64 + i] + sMom[96 + i];
    }
    outp[e] = a;
  }
}

// Reduce partials across the 1024 groups (fp64) -> sred[560]
__global__ __launch_bounds__(256) void nca_reduceA(
    const float* __restrict__ partials, double* __restrict__ sred) {
  __shared__ double red[256];
  int e = blockIdx.x;
  int t = threadIdx.x;
  double acc = 0.0;
  for (int row = t; row < NGRP; row += 256)
    acc += (double)partials[(size_t)row * NSTAT + e];
  red[t] = acc;
  __syncthreads();
  for (int s2 = 128; s2 > 0; s2 >>= 1) {
    if (t < s2) red[t] += red[t + s2];
    __syncthreads();
  }
  if (t == 0) sred[e] = red[0];
}

// Per-hid BN constants from moments. fc0_b cancels exactly.
__global__ __launch_bounds__(128) void nca_reduceB(
    const double* __restrict__ sred, const float* __restrict__ fc0w,
    const float* __restrict__ gamma, const float* __restrict__ beta,
    float* __restrict__ ss) {
  __shared__ double S[NSTAT];
  int t = threadIdx.x;
  for (int i = t; i < NSTAT; i += 128) S[i] = sred[i];
  __syncthreads();
  double wv[32];
#pragma unroll
  for (int k = 0; k < 32; k++) wv[k] = (double)fc0w[k * HIDn + t];
  double mean_g = 0.0, q = 0.0;
  int e = 0;
  for (int i = 0; i < 32; i++) {
    mean_g += wv[i] * S[NPAIR + i];
    q += wv[i] * wv[i] * S[e]; e++;
    for (int j = i + 1; j < 32; j++) { q += 2.0 * wv[i] * wv[j] * S[e]; e++; }
  }
  const double invN = 1.0 / (double)NCELLS;
  mean_g *= invN; q *= invN;
  double var = q - mean_g * mean_g;
  double scale = (double)gamma[t] / sqrt(var + 1e-5);
  ss[2 * t]     = (float)scale;
  ss[2 * t + 1] = (float)((double)beta[t] - mean_g * scale);
}

// MFMA update: per wave, 16-cell M-tiles. fc0: 8x mfma_16x16x32_bf16 (K=32);
// BN+relu on f32 accs; repack bf16 via per-wave LDS (XOR swizzle, k-permuted);
// fc1: 4x mfma_16x16x32_bf16 (K=128); residual+mask epilogue.
__global__ __launch_bounds__(256) void nca_update_mfma(
    const float* __restrict__ x, const uint16_t* __restrict__ ybf,
    const uint16_t* __restrict__ w0bf, const uint16_t* __restrict__ w1p,
    const float* __restrict__ ssg, float* __restrict__ xout,
    uint32_t fk0, uint32_t fk1) {
  __shared__ short hbuf[4][16 * 128];  // 4KB per wave
  int t = threadIdx.x;
  int lane = t & 63, wid = t >> 6;
  int col = lane & 15, g = lane >> 4;
  short* hb = hbuf[wid];

  bf16x8 b0[8];
#pragma unroll
  for (int nt = 0; nt < 8; nt++) {
    int n = nt * 16 + col;
    b0[nt] = *reinterpret_cast<const bf16x8*>(w0bf + n * 32 + g * 8);
  }
  bf16x8 b2[4];
#pragma unroll
  for (int kk = 0; kk < 4; kk++)
    b2[kk] = *reinterpret_cast<const bf16x8*>(w1p + col * 128 + kk * 32 + g * 8);
  float sc[8], sh[8];
#pragma unroll
  for (int nt = 0; nt < 8; nt++) {
    float2 v = reinterpret_cast<const float2*>(ssg)[nt * 16 + col];
    sc[nt] = v.x; sh[nt] = v.y;
  }

  uint32_t waveBase = (uint32_t)blockIdx.x * 1024u + (uint32_t)wid * 256u;
  for (int grp = 0; grp < 4; grp++) {
    uint32_t grpBase = waveBase + (uint32_t)grp * 64u;
    float mval = cell_mask(fk0, fk1, grpBase + (uint32_t)lane);
#pragma unroll 1
    for (int tt = 0; tt < 4; tt++) {
      uint32_t tb = grpBase + (uint32_t)tt * 16u;
      bf16x8 a0 = *reinterpret_cast<const bf16x8*>(
          ybf + (size_t)(tb + col) * 32 + g * 8);
      float xv[4];
#pragma unroll
      for (int r = 0; r < 4; r++)
        xv[r] = x[(size_t)(tb + g * 4 + r) * Cn + col];
      f32x4 h[8];
#pragma unroll
      for (int nt = 0; nt < 8; nt++) {
        f32x4 z = {0.f, 0.f, 0.f, 0.f};
        h[nt] = __builtin_amdgcn_mfma_f32_16x16x32_bf16(a0, b0[nt], z, 0, 0, 0);
      }
#pragma unroll
      for (int r = 0; r < 4; r++) {
        int m = g * 4 + r;
        uint32_t u[4];
#pragma unroll
        for (int q = 0; q < 4; q++) {
          float v0 = fmaxf(h[2 * q][r] * sc[2 * q] + sh[2 * q], 0.0f);
          float v1 = fmaxf(h[2 * q + 1][r] * sc[2 * q + 1] + sh[2 * q + 1], 0.0f);
          u[q] = f2bf(v0) | (f2bf(v1) << 16);
        }
        int idx = m * 128 + ((col * 8) ^ ((m & 7) << 3));
        *reinterpret_cast<uint4*>(hb + idx) = make_uint4(u[0], u[1], u[2], u[3]);
      }
      f32x4 dx = {0.f, 0.f, 0.f, 0.f};
#pragma unroll
      for (int kk = 0; kk < 4; kk++) {
        int idx = col * 128 + (((kk * 32) + g * 8) ^ ((col & 7) << 3));
        bf16x8 a2 = *reinterpret_cast<const bf16x8*>(hb + idx);
        dx = __builtin_amdgcn_mfma_f32_16x16x32_bf16(a2, b2[kk], dx, 0, 0, 0);
      }
#pragma unroll
      for (int r = 0; r < 4; r++) {
        int m = g * 4 + r;
        float mk = __shfl(mval, tt * 16 + m);
        float o = xv[r] + dx[r] * mk;
        if (col == 0) o = xv[r];
        xout[(size_t)(tb + m) * Cn + col] = o;
      }
    }
  }
}

extern "C" void kernel_launch(void* const* d_in, const int* in_sizes, int n_in,
                              void* d_out, int out_size, void* d_ws, size_t ws_size,
                              hipStream_t stream) {
  (void)in_sizes; (void)n_in; (void)out_size; (void)ws_size;
  const float* x0    = (const float*)d_in[0];
  const float* p0w   = (const float*)d_in[1];
  const float* p0b   = (const float*)d_in[2];
  const float* fc0w  = (const float*)d_in[3];
  // d_in[4] = fc0_b: cancels exactly in BatchNorm -> unused
  const float* gamma = (const float*)d_in[5];
  const float* beta  = (const float*)d_in[6];
  const float* fc1w  = (const float*)d_in[7];
  // d_in[8] = steps (=10, hardcoded)

  // workspace layout (~70 MB)
  size_t off = 0;
  float* ws_x = (float*)((char*)d_ws + off); off += (size_t)NCELLS * Cn * 4;        // 33.5 MiB
  uint16_t* ws_ybf = (uint16_t*)((char*)d_ws + off); off += (size_t)NCELLS * 32 * 2; // 33.5 MiB
  float* ws_part = (float*)((char*)d_ws + off); off += (size_t)NGRP * NSTAT * 4;    // 2.3 MiB
  double* ws_sred = (double*)((char*)d_ws + off); off += (size_t)NSTAT * 8;
  float* ws_ss = (float*)((char*)d_ws + off); off += (size_t)HIDn * 2 * 4;
  uint16_t* ws_w0bf = (uint16_t*)((char*)d_ws + off); off += 4096 * 2;
  uint16_t* ws_w1p = (uint16_t*)((char*)d_ws + off); off += 2048 * 2;
  float* out = (float*)d_out;

  nca_prep<<<24, 256, 0, stream>>>(fc0w, fc1w, ws_w0bf, ws_w1p);

  const float* xin = x0;
  for (int s = 0; s < STEPS; s++) {
    uint32_t fk0 = 0u, fk1 = (uint32_t)s;
    tf2x32(0u, 42u, fk0, fk1);
    float* xo = (((STEPS - 1 - s) & 1) != 0) ? ws_x : out;

    nca_convgram<<<NGRP, 256, 0, stream>>>(xin, p0w, p0b, ws_ybf, ws_part);
    nca_reduceA<<<NSTAT, 256, 0, stream>>>(ws_part, ws_sred);
    nca_reduceB<<<1, 128, 0, stream>>>(ws_sred, fc0w, gamma, beta, ws_ss);
    nca_update_mfma<<<NCELLS / 1024, 256, 0, stream>>>(xin, ws_ybf, ws_w0bf,
                                                       ws_w1p, ws_ss, xo, fk0, fk1);
    xin = xo;
  }
}